// Round 9
// baseline (309.865 us; speedup 1.0000x reference)
//
#include <hip/hip_runtime.h>
#include <math.h>

#define N_NODES 100000
#define N_EDGES 3200000
#define IN_CH 256
#define NC 20        // combined output channels (10 mu + 10 logstd)
#define OC 10
#define NPB 128      // nodes per bucket (col >> 7)
#define NBUCK 782    // ceil(100000/128)
#define CAP 4864     // per-bucket capacity: mean 4096, sigma ~64 -> +12 sigma

// binning geometry: LDS counting sort, coalesced flush
#define CHUNK3 8192          // edges per bin-role block
#define NCHUNK3 391          // ceil(3.2M/8192)
#define NGEMMB 196           // ceil(100000/512) gemm-role blocks (512 nodes each)
#define NMEGA 587            // NCHUNK3 + NGEMMB

// ---------- init per-bucket allocation cursors ----------
__global__ __launch_bounds__(256) void k_initptr(int* __restrict__ bptr) {
    int i = blockIdx.x * 256 + threadIdx.x;
    if (i < NBUCK) bptr[i] = i * CAP;
}

// ---------- bf16 pack helpers (RNE) ----------
__device__ __forceinline__ unsigned bfpack(float a, float b) {
    unsigned ua = __float_as_uint(a), ub = __float_as_uint(b);
    ua = (ua + 0x7FFFu + ((ua >> 16) & 1u)) >> 16;
    ub = (ub + 0x7FFFu + ((ub >> 16) & 1u)) >> 16;
    return ua | (ub << 16);
}
__device__ __forceinline__ float bflo(unsigned p) { return __uint_as_float(p << 16); }
__device__ __forceinline__ float bfhi(unsigned p) { return __uint_as_float(p & 0xFFFF0000u); }

// ---------- LDS overlays for the two block roles ----------
struct BinSmem {
    int lh[NBUCK];       // counts -> scatter cursor
    int lscan[NBUCK];    // inclusive scan
    int gmino[NBUCK];    // gbase - lofs
    int stage[CHUNK3];   // bucket-sorted packed pairs
    unsigned short sbkt[CHUNK3];
};
struct GemmSmem { float sW[NC * 272]; };
union MegaSmem { BinSmem b; GemmSmem g; };

// ---------- MEGA: bin (R1-proven) and gemm (R4-proven) overlapped on the device ----------
// Both roles are latency-bound alone (all pipes <30%); co-residency fills the
// idle issue slots. Interleaved role mapping mixes both types on each CU.
// gemm stores RAW bf16 h (no dinv prescale) -> no dependency on binning.
__global__ __launch_bounds__(1024) void k_mega(const int* __restrict__ row,
                                               const int* __restrict__ col,
                                               int* __restrict__ bptr,
                                               int* __restrict__ bpairs,
                                               const float* __restrict__ x,
                                               const float* __restrict__ Wmu,
                                               const float* __restrict__ Wls,
                                               uint4* __restrict__ hbA,
                                               uint4* __restrict__ hbB,
                                               uint2* __restrict__ hbC) {
    __shared__ MegaSmem sm;
    int bid = blockIdx.x;
    int t = threadIdx.x;
    bool isGemm = (bid < 2 * NGEMMB) && (bid & 1);

    if (!isGemm) {
        // ================= bin role (verbatim bin3 logic) =================
        int cb = (bid < 2 * NGEMMB) ? (bid >> 1) : (bid - NGEMMB);
        int e0 = cb * CHUNK3;
        int nE = N_EDGES - e0; if (nE > CHUNK3) nE = CHUNK3;
        int n4 = nE >> 2;
        const int4* c4 = (const int4*)(col + e0);
        const int4* r4 = (const int4*)(row + e0);

        for (int i = t; i < NBUCK; i += 1024) sm.b.lh[i] = 0;
        __syncthreads();

        for (int j = t; j < n4; j += 1024) {
            int4 c = c4[j];
            atomicAdd(&sm.b.lh[c.x >> 7], 1); atomicAdd(&sm.b.lh[c.y >> 7], 1);
            atomicAdd(&sm.b.lh[c.z >> 7], 1); atomicAdd(&sm.b.lh[c.w >> 7], 1);
        }
        __syncthreads();

        int cnt = 0;
        if (t < NBUCK) { cnt = sm.b.lh[t]; sm.b.lscan[t] = cnt; }
        __syncthreads();
        for (int o = 1; o < NBUCK; o <<= 1) {
            int add = 0;
            if (t < NBUCK && t >= o) add = sm.b.lscan[t - o];
            __syncthreads();
            if (t < NBUCK) sm.b.lscan[t] += add;
            __syncthreads();
        }
        if (t < NBUCK) {
            int lofs = sm.b.lscan[t] - cnt;
            int gbase = cnt ? atomicAdd(&bptr[t], cnt) : 0;
            sm.b.gmino[t] = gbase - lofs;
            sm.b.lh[t] = lofs;
        }
        __syncthreads();

        for (int j = t; j < n4; j += 1024) {
            int4 c = c4[j];
            int4 r = r4[j];
            int b0 = c.x >> 7, b1 = c.y >> 7, b2 = c.z >> 7, b3 = c.w >> 7;
            int s0 = atomicAdd(&sm.b.lh[b0], 1);
            int s1 = atomicAdd(&sm.b.lh[b1], 1);
            int s2 = atomicAdd(&sm.b.lh[b2], 1);
            int s3 = atomicAdd(&sm.b.lh[b3], 1);
            sm.b.stage[s0] = (r.x << 7) | (c.x & 127); sm.b.sbkt[s0] = (unsigned short)b0;
            sm.b.stage[s1] = (r.y << 7) | (c.y & 127); sm.b.sbkt[s1] = (unsigned short)b1;
            sm.b.stage[s2] = (r.z << 7) | (c.z & 127); sm.b.sbkt[s2] = (unsigned short)b2;
            sm.b.stage[s3] = (r.w << 7) | (c.w & 127); sm.b.sbkt[s3] = (unsigned short)b3;
        }
        __syncthreads();

        for (int j = t; j < nE; j += 1024) {
            int b = sm.b.sbkt[j];
            int dst = sm.b.gmino[b] + j;
            if (dst < (b + 1) * CAP) bpairs[dst] = sm.b.stage[j];
        }
    } else {
        // ================= gemm role (verbatim gemm6s compute, raw-h store) =========
        // unroll-4 keeps the 4 loads of each 64B x-line consecutive (R5 lesson).
        int gb = bid >> 1;
        for (int idx = t; idx < IN_CH * OC; idx += 1024) {
            int k = idx / OC, c = idx - (idx / OC) * OC;
            int kk = k >> 6, j = k & 63;
            sm.g.sW[c * 272 + kk * 68 + j]        = Wmu[idx];
            sm.g.sW[(c + OC) * 272 + kk * 68 + j] = Wls[idx];
        }
        __syncthreads();

        int kk = t & 3;
        int slot = t >> 2;                       // 0..255
        int n0 = gb * 512 + slot;                // thread's nodes: n0, n0+256

        int nd[2];
#pragma unroll
        for (int u = 0; u < 2; u++) {
            int n = n0 + u * 256;
            nd[u] = (n < N_NODES) ? n : (N_NODES - 1);
        }

        float acc[2][NC];
#pragma unroll
        for (int u = 0; u < 2; u++)
#pragma unroll
            for (int c = 0; c < NC; c++) acc[u][c] = 0.0f;

        const float4* x4 = (const float4*)x;

#pragma unroll 4
        for (int j4 = 0; j4 < 16; j4++) {
            float4 xv0 = x4[(size_t)nd[0] * 64 + kk * 16 + j4];
            float4 xv1 = x4[(size_t)nd[1] * 64 + kk * 16 + j4];
#pragma unroll
            for (int c = 0; c < NC; c++) {
                float4 w = *(const float4*)&sm.g.sW[c * 272 + kk * 68 + j4 * 4];
                acc[0][c] += xv0.x * w.x + xv0.y * w.y + xv0.z * w.z + xv0.w * w.w;
                acc[1][c] += xv1.x * w.x + xv1.y * w.y + xv1.z * w.z + xv1.w * w.w;
            }
        }

#pragma unroll
        for (int u = 0; u < 2; u++)
#pragma unroll
            for (int c = 0; c < NC; c++) {
                acc[u][c] += __shfl_xor(acc[u][c], 2);
                acc[u][c] += __shfl_xor(acc[u][c], 1);
            }

        if (kk == 0) {
#pragma unroll
            for (int u = 0; u < 2; u++) {
                int n = n0 + u * 256;
                if (n >= N_NODES) continue;
                hbA[n] = make_uint4(bfpack(acc[u][0],  acc[u][1]),
                                    bfpack(acc[u][2],  acc[u][3]),
                                    bfpack(acc[u][4],  acc[u][5]),
                                    bfpack(acc[u][6],  acc[u][7]));
                hbB[n] = make_uint4(bfpack(acc[u][8],  acc[u][9]),
                                    bfpack(acc[u][10], acc[u][11]),
                                    bfpack(acc[u][12], acc[u][13]),
                                    bfpack(acc[u][14], acc[u][15]));
                hbC[n] = make_uint2(bfpack(acc[u][16], acc[u][17]),
                                    bfpack(acc[u][18], acc[u][19]));
            }
        }
    }
}

// ---------- per-node degree from bucket regions; dinv = rsqrt(deg+1) ----------
__global__ __launch_bounds__(256) void k_deg(const int* __restrict__ bptr,
                                             const int* __restrict__ bpairs,
                                             float* __restrict__ dinv) {
    __shared__ int lc[NPB];
    int b = blockIdx.x, t = threadIdx.x;
    if (t < NPB) lc[t] = 0;
    __syncthreads();
    int start = b * CAP;
    int n = bptr[b] - start; if (n > CAP) n = CAP;
    for (int p = t; p < n; p += 256)
        atomicAdd(&lc[bpairs[start + p] & 127], 1);
    __syncthreads();
    int node = b * NPB + t;
    if (t < NPB && node < N_NODES)
        dinv[node] = rsqrtf((float)(lc[t] + 1));   // +1 self loop
}

// ---------- fused sort+reduce per 128-node bucket ----------
// agg7 structure + 4th independent gather dinv[src] (h is raw bf16 now).
__global__ __launch_bounds__(512) void k_agg8(const int* __restrict__ bptr,
                                              const int* __restrict__ bpairs,
                                              const uint4* __restrict__ hbA,
                                              const uint4* __restrict__ hbB,
                                              const uint2* __restrict__ hbC,
                                              const float* __restrict__ dinv,
                                              const float* __restrict__ bmu,
                                              const float* __restrict__ bls,
                                              float* __restrict__ out) {
    __shared__ int lcnt[NPB];    // hist -> cursor
    __shared__ int lscan[NPB];   // inclusive scan
    __shared__ int sCnt[NPB];    // per-node count
    __shared__ int ssrc[CAP];    // node-sorted src ids
    int b = blockIdx.x, t = threadIdx.x;
    int start = b * CAP;
    int n = bptr[b] - start; if (n > CAP) n = CAP;

    if (t < NPB) lcnt[t] = 0;
    __syncthreads();
    for (int p = t; p < n; p += 512)
        atomicAdd(&lcnt[bpairs[start + p] & 127], 1);
    __syncthreads();

    int cnt = 0;
    if (t < NPB) { cnt = lcnt[t]; lscan[t] = cnt; sCnt[t] = cnt; }
    __syncthreads();
    for (int o = 1; o < NPB; o <<= 1) {
        int add = 0;
        if (t < NPB && t >= o) add = lscan[t - o];
        __syncthreads();
        if (t < NPB) lscan[t] += add;
        __syncthreads();
    }
    if (t < NPB) lcnt[t] = lscan[t] - cnt;   // cursor = exclusive
    __syncthreads();

    for (int p = t; p < n; p += 512) {
        int pk = bpairs[start + p];
        int q = atomicAdd(&lcnt[pk & 127], 1);
        ssrc[q] = ((unsigned)pk) >> 7;
    }
    __syncthreads();

    // reduce: 4 threads per node, quad edge-split, shuffle combine (xor 1,2)
    int nl = t >> 2, quarter = t & 3;
    int node = b * NPB + nl;
    int ccnt = sCnt[nl];
    int base = lscan[nl] - ccnt;
    int j0 = (ccnt * quarter) >> 2;
    int j1 = (ccnt * (quarter + 1)) >> 2;

    float a[NC];
#pragma unroll
    for (int c = 0; c < NC; c++) a[c] = 0.0f;

#define ADDROW(R, S)                                                     \
    {                                                                    \
        uint4 qa = hbA[(R)];                                             \
        uint4 qb = hbB[(R)];                                             \
        uint2 qc = hbC[(R)];                                             \
        float s_ = (S);                                                  \
        a[0]  += s_ * bflo(qa.x); a[1]  += s_ * bfhi(qa.x);              \
        a[2]  += s_ * bflo(qa.y); a[3]  += s_ * bfhi(qa.y);              \
        a[4]  += s_ * bflo(qa.z); a[5]  += s_ * bfhi(qa.z);              \
        a[6]  += s_ * bflo(qa.w); a[7]  += s_ * bfhi(qa.w);              \
        a[8]  += s_ * bflo(qb.x); a[9]  += s_ * bfhi(qb.x);              \
        a[10] += s_ * bflo(qb.y); a[11] += s_ * bfhi(qb.y);              \
        a[12] += s_ * bflo(qb.z); a[13] += s_ * bfhi(qb.z);              \
        a[14] += s_ * bflo(qb.w); a[15] += s_ * bfhi(qb.w);              \
        a[16] += s_ * bflo(qc.x); a[17] += s_ * bfhi(qc.x);              \
        a[18] += s_ * bflo(qc.y); a[19] += s_ * bfhi(qc.y);              \
    }

    int j = j0;
    for (; j + 1 < j1; j += 2) {
        int r0 = ssrc[base + j];
        int r1 = ssrc[base + j + 1];
        float s0 = dinv[r0];
        float s1 = dinv[r1];
        ADDROW(r0, s0);
        ADDROW(r1, s1);
    }
    if (j < j1) {
        int r0 = ssrc[base + j];
        ADDROW(r0, dinv[r0]);
    }
    // self loop on the quarter-0 thread (raw h scaled by dinv[node])
    if (quarter == 0 && node < N_NODES) ADDROW(node, dinv[node]);
#undef ADDROW

#pragma unroll
    for (int c = 0; c < NC; c++) {
        a[c] += __shfl_xor(a[c], 1);
        a[c] += __shfl_xor(a[c], 2);
    }

    if (quarter == 0 && node < N_NODES) {
        float dn = rsqrtf((float)(ccnt + 1));
        float* om = out + (size_t)node * OC;
        float* ol = out + (size_t)N_NODES * OC + (size_t)node * OC;
#pragma unroll
        for (int c = 0; c < OC; c++) {
            om[c] = dn * a[c]      + bmu[c];
            ol[c] = dn * a[c + OC] + bls[c];
        }
    }
}

// ======================= fallback (atomic scatter path, tiny ws) =======================
__global__ __launch_bounds__(256) void k_init_deg(float* __restrict__ deg) {
    int i = blockIdx.x * 256 + threadIdx.x;
    if (i < N_NODES) deg[i] = 1.0f;
}
__global__ __launch_bounds__(256) void k_count(const int* __restrict__ col, float* __restrict__ deg) {
    int e = blockIdx.x * 256 + threadIdx.x;
    if (e < N_EDGES) atomicAdd(&deg[col[e]], 1.0f);
}
__global__ __launch_bounds__(256) void k_dinvk(float* __restrict__ deg) {
    int i = blockIdx.x * 256 + threadIdx.x;
    if (i < N_NODES) deg[i] = rsqrtf(deg[i]);
}
__global__ __launch_bounds__(256) void k_gemm_f32(const float* __restrict__ x,
                                                  const float* __restrict__ Wmu,
                                                  const float* __restrict__ Wls,
                                                  float* __restrict__ h) {
    int node = blockIdx.x * 256 + threadIdx.x;
    if (node >= N_NODES) return;
    const float4* x4 = (const float4*)(x + (size_t)node * IN_CH);
    float acc[NC];
#pragma unroll
    for (int c = 0; c < NC; c++) acc[c] = 0.0f;
    for (int k4 = 0; k4 < IN_CH / 4; k4++) {
        float4 xv = x4[k4];
        float xk[4] = {xv.x, xv.y, xv.z, xv.w};
#pragma unroll
        for (int kk = 0; kk < 4; kk++) {
            const float* wm = Wmu + (k4 * 4 + kk) * OC;
            const float* wl = Wls + (k4 * 4 + kk) * OC;
#pragma unroll
            for (int c = 0; c < OC; c++) {
                acc[c]      += xk[kk] * wm[c];
                acc[c + OC] += xk[kk] * wl[c];
            }
        }
    }
    float* hp = h + (size_t)node * NC;
#pragma unroll
    for (int c = 0; c < NC; c++) hp[c] = acc[c];
}
__global__ __launch_bounds__(256) void k_scatter(const int* __restrict__ row, const int* __restrict__ col,
                                                 const float* __restrict__ dinv, const float* __restrict__ h,
                                                 float* __restrict__ out) {
    int e = blockIdx.x * 256 + threadIdx.x;
    if (e >= N_EDGES) return;
    int r = row[e], c = col[e];
    float s = dinv[r] * dinv[c];
    const float* hp = h + (size_t)r * NC;
    float* om = out + (size_t)c * OC;
    float* ol = om + (size_t)N_NODES * OC;
#pragma unroll
    for (int k = 0; k < OC; k++) atomicAdd(om + k, hp[k] * s);
#pragma unroll
    for (int k = 0; k < OC; k++) atomicAdd(ol + k, hp[OC + k] * s);
}
__global__ __launch_bounds__(256) void k_final(const float* __restrict__ h, const float* __restrict__ dinv,
                                               const float* __restrict__ bmu, const float* __restrict__ bls,
                                               float* __restrict__ out) {
    int i = blockIdx.x * 256 + threadIdx.x;
    if (i >= N_NODES * OC) return;
    int node = i / OC, c = i - node * OC;
    float d = dinv[node];
    float d2 = d * d;
    out[i]                += h[node * NC + c]      * d2 + bmu[c];
    out[N_NODES * OC + i] += h[node * NC + OC + c] * d2 + bls[c];
}

extern "C" void kernel_launch(void* const* d_in, const int* in_sizes, int n_in,
                              void* d_out, int out_size, void* d_ws, size_t ws_size,
                              hipStream_t stream) {
    const float* x   = (const float*)d_in[0];
    const int*   ei  = (const int*)d_in[1];
    const float* Wmu = (const float*)d_in[2];
    const float* bmu = (const float*)d_in[3];
    const float* Wls = (const float*)d_in[4];
    const float* bls = (const float*)d_in[5];
    float* out = (float*)d_out;

    const int* row = ei;            // edge_index[0] (sources)
    const int* col = ei + N_EDGES;  // edge_index[1] (targets)

    // ws layout (unchanged footprint):
    //   bptr   int[NBUCK]       @ 0        (3.1 KB)
    //   dinv   f32[100096]      @ 8 KB     (400 KB)
    //   hbA    uint4[100000]    @ 512 KB   (1.6 MB)  \
    //   hbB    uint4[100000]    @ +1.6 MB  (1.6 MB)   } SoA bf16 RAW h (4 MB)
    //   hbC    uint2[100000]    @ +3.2 MB  (0.8 MB)  /
    //   bpairs int[NBUCK*CAP]   @ 4.5 MB   (15.2 MB)
    const size_t BPAIRS_OFF = (size_t)(9 << 19);   // 4.5 MiB
    const size_t REQ = BPAIRS_OFF + (size_t)NBUCK * CAP * 4;

    if (ws_size >= REQ) {
        char* w = (char*)d_ws;
        int*      bptr   = (int*)(w);
        float*    dinv   = (float*)(w + 8192);
        uint4*    hbA    = (uint4*)(w + (512 << 10));
        uint4*    hbB    = (uint4*)(w + (512 << 10) + 1600000);
        uint2*    hbC    = (uint2*)(w + (512 << 10) + 3200000);
        int*      bpairs = (int*)(w + BPAIRS_OFF);

        k_initptr<<<(NBUCK + 255) / 256, 256, 0, stream>>>(bptr);
        k_mega<<<NMEGA, 1024, 0, stream>>>(row, col, bptr, bpairs, x, Wmu, Wls, hbA, hbB, hbC);
        k_deg<<<NBUCK, 256, 0, stream>>>(bptr, bpairs, dinv);
        k_agg8<<<NBUCK, 512, 0, stream>>>(bptr, bpairs, hbA, hbB, hbC, dinv, bmu, bls, out);
    } else {
        float* deg = (float*)d_ws;
        float* h   = (float*)((char*)d_ws + (1 << 20));
        hipMemsetAsync(d_out, 0, (size_t)out_size * sizeof(float), stream);
        k_init_deg<<<(N_NODES + 255) / 256, 256, 0, stream>>>(deg);
        k_count<<<(N_EDGES + 255) / 256, 256, 0, stream>>>(col, deg);
        k_dinvk<<<(N_NODES + 255) / 256, 256, 0, stream>>>(deg);
        k_gemm_f32<<<(N_NODES + 255) / 256, 256, 0, stream>>>(x, Wmu, Wls, h);
        k_scatter<<<(N_EDGES + 255) / 256, 256, 0, stream>>>(row, col, deg, h, out);
        k_final<<<(N_NODES * OC + 255) / 256, 256, 0, stream>>>(h, deg, bmu, bls, out);
    }
}

// Round 10
// 297.399 us; speedup vs baseline: 1.0419x; 1.0419x over previous
//
#include <hip/hip_runtime.h>
#include <math.h>

#define N_NODES 100000
#define N_EDGES 3200000
#define IN_CH 256
#define NC 20        // combined output channels (10 mu + 10 logstd)
#define OC 10
#define NPB 128      // nodes per bucket (col >> 7)
#define NBUCK 782    // ceil(100000/128)
#define CAP 4864     // per-bucket capacity: mean 4096, sigma ~64 -> +12 sigma

// binning geometry: LDS counting sort, coalesced flush
#define CHUNK3 8192          // edges per bin-role block
#define NCHUNK3 391          // ceil(3.2M/8192)
#define NGEMMB 196           // ceil(100000/512) gemm-role blocks (512 nodes each)
#define NMEGA 587            // NCHUNK3 + NGEMMB

// ---------- init per-bucket allocation cursors ----------
__global__ __launch_bounds__(256) void k_initptr(int* __restrict__ bptr) {
    int i = blockIdx.x * 256 + threadIdx.x;
    if (i < NBUCK) bptr[i] = i * CAP;
}

// ---------- bf16 pack helpers (RNE) ----------
__device__ __forceinline__ unsigned bfpack(float a, float b) {
    unsigned ua = __float_as_uint(a), ub = __float_as_uint(b);
    ua = (ua + 0x7FFFu + ((ua >> 16) & 1u)) >> 16;
    ub = (ub + 0x7FFFu + ((ub >> 16) & 1u)) >> 16;
    return ua | (ub << 16);
}
__device__ __forceinline__ float bflo(unsigned p) { return __uint_as_float(p << 16); }
__device__ __forceinline__ float bfhi(unsigned p) { return __uint_as_float(p & 0xFFFF0000u); }

// ---------- LDS overlays for the two mega roles ----------
struct BinSmem {
    int lh[NBUCK];       // counts -> scatter cursor
    int lscan[NBUCK];    // inclusive scan
    int gmino[NBUCK];    // gbase - lofs
    int stage[CHUNK3];   // bucket-sorted packed pairs
    unsigned short sbkt[CHUNK3];
};
struct GemmSmem { float sW[NC * 272]; };
union MegaSmem { BinSmem b; GemmSmem g; };

// ---------- MEGA (R9-proven overlap): bin + gemm co-resident; gemm stores fp32 h ----------
// R9 post-mortem: overlap saved 26us (98.8 vs 125 serial). The dinv coupling is
// now solved in node-space (k_degs), NOT per-edge (agg8's +53us mistake).
__global__ __launch_bounds__(1024) void k_mega32(const int* __restrict__ row,
                                                 const int* __restrict__ col,
                                                 int* __restrict__ bptr,
                                                 int* __restrict__ bpairs,
                                                 const float* __restrict__ x,
                                                 const float* __restrict__ Wmu,
                                                 const float* __restrict__ Wls,
                                                 float* __restrict__ h32) {
    __shared__ MegaSmem sm;
    int bid = blockIdx.x;
    int t = threadIdx.x;
    bool isGemm = (bid < 2 * NGEMMB) && (bid & 1);

    if (!isGemm) {
        // ================= bin role (verbatim bin3 logic) =================
        int cb = (bid < 2 * NGEMMB) ? (bid >> 1) : (bid - NGEMMB);
        int e0 = cb * CHUNK3;
        int nE = N_EDGES - e0; if (nE > CHUNK3) nE = CHUNK3;
        int n4 = nE >> 2;
        const int4* c4 = (const int4*)(col + e0);
        const int4* r4 = (const int4*)(row + e0);

        for (int i = t; i < NBUCK; i += 1024) sm.b.lh[i] = 0;
        __syncthreads();

        for (int j = t; j < n4; j += 1024) {
            int4 c = c4[j];
            atomicAdd(&sm.b.lh[c.x >> 7], 1); atomicAdd(&sm.b.lh[c.y >> 7], 1);
            atomicAdd(&sm.b.lh[c.z >> 7], 1); atomicAdd(&sm.b.lh[c.w >> 7], 1);
        }
        __syncthreads();

        int cnt = 0;
        if (t < NBUCK) { cnt = sm.b.lh[t]; sm.b.lscan[t] = cnt; }
        __syncthreads();
        for (int o = 1; o < NBUCK; o <<= 1) {
            int add = 0;
            if (t < NBUCK && t >= o) add = sm.b.lscan[t - o];
            __syncthreads();
            if (t < NBUCK) sm.b.lscan[t] += add;
            __syncthreads();
        }
        if (t < NBUCK) {
            int lofs = sm.b.lscan[t] - cnt;
            int gbase = cnt ? atomicAdd(&bptr[t], cnt) : 0;
            sm.b.gmino[t] = gbase - lofs;
            sm.b.lh[t] = lofs;
        }
        __syncthreads();

        for (int j = t; j < n4; j += 1024) {
            int4 c = c4[j];
            int4 r = r4[j];
            int b0 = c.x >> 7, b1 = c.y >> 7, b2 = c.z >> 7, b3 = c.w >> 7;
            int s0 = atomicAdd(&sm.b.lh[b0], 1);
            int s1 = atomicAdd(&sm.b.lh[b1], 1);
            int s2 = atomicAdd(&sm.b.lh[b2], 1);
            int s3 = atomicAdd(&sm.b.lh[b3], 1);
            sm.b.stage[s0] = (r.x << 7) | (c.x & 127); sm.b.sbkt[s0] = (unsigned short)b0;
            sm.b.stage[s1] = (r.y << 7) | (c.y & 127); sm.b.sbkt[s1] = (unsigned short)b1;
            sm.b.stage[s2] = (r.z << 7) | (c.z & 127); sm.b.sbkt[s2] = (unsigned short)b2;
            sm.b.stage[s3] = (r.w << 7) | (c.w & 127); sm.b.sbkt[s3] = (unsigned short)b3;
        }
        __syncthreads();

        for (int j = t; j < nE; j += 1024) {
            int b = sm.b.sbkt[j];
            int dst = sm.b.gmino[b] + j;
            if (dst < (b + 1) * CAP) bpairs[dst] = sm.b.stage[j];
        }
    } else {
        // ================= gemm role (verbatim compute; fp32 h store) ================
        // unroll-4 keeps the 4 loads of each 64B x-line consecutive (R5 lesson).
        int gb = bid >> 1;
        for (int idx = t; idx < IN_CH * OC; idx += 1024) {
            int k = idx / OC, c = idx - (idx / OC) * OC;
            int kk = k >> 6, j = k & 63;
            sm.g.sW[c * 272 + kk * 68 + j]        = Wmu[idx];
            sm.g.sW[(c + OC) * 272 + kk * 68 + j] = Wls[idx];
        }
        __syncthreads();

        int kk = t & 3;
        int slot = t >> 2;                       // 0..255
        int n0 = gb * 512 + slot;                // thread's nodes: n0, n0+256

        int nd[2];
#pragma unroll
        for (int u = 0; u < 2; u++) {
            int n = n0 + u * 256;
            nd[u] = (n < N_NODES) ? n : (N_NODES - 1);
        }

        float acc[2][NC];
#pragma unroll
        for (int u = 0; u < 2; u++)
#pragma unroll
            for (int c = 0; c < NC; c++) acc[u][c] = 0.0f;

        const float4* x4 = (const float4*)x;

#pragma unroll 4
        for (int j4 = 0; j4 < 16; j4++) {
            float4 xv0 = x4[(size_t)nd[0] * 64 + kk * 16 + j4];
            float4 xv1 = x4[(size_t)nd[1] * 64 + kk * 16 + j4];
#pragma unroll
            for (int c = 0; c < NC; c++) {
                float4 w = *(const float4*)&sm.g.sW[c * 272 + kk * 68 + j4 * 4];
                acc[0][c] += xv0.x * w.x + xv0.y * w.y + xv0.z * w.z + xv0.w * w.w;
                acc[1][c] += xv1.x * w.x + xv1.y * w.y + xv1.z * w.z + xv1.w * w.w;
            }
        }

#pragma unroll
        for (int u = 0; u < 2; u++)
#pragma unroll
            for (int c = 0; c < NC; c++) {
                acc[u][c] += __shfl_xor(acc[u][c], 2);
                acc[u][c] += __shfl_xor(acc[u][c], 1);
            }

        if (kk == 0) {
#pragma unroll
            for (int u = 0; u < 2; u++) {
                int n = n0 + u * 256;
                if (n >= N_NODES) continue;
                float* hp = h32 + (size_t)n * NC;
                *(float4*)(hp + 0)  = make_float4(acc[u][0],  acc[u][1],  acc[u][2],  acc[u][3]);
                *(float4*)(hp + 4)  = make_float4(acc[u][4],  acc[u][5],  acc[u][6],  acc[u][7]);
                *(float4*)(hp + 8)  = make_float4(acc[u][8],  acc[u][9],  acc[u][10], acc[u][11]);
                *(float4*)(hp + 12) = make_float4(acc[u][12], acc[u][13], acc[u][14], acc[u][15]);
                *(float4*)(hp + 16) = make_float4(acc[u][16], acc[u][17], acc[u][18], acc[u][19]);
            }
        }
    }
}

// ---------- degree count + node-space scale/pack (fp32 h -> bf16 SoA, ONE rounding) ----------
__global__ __launch_bounds__(256) void k_degs(const int* __restrict__ bptr,
                                              const int* __restrict__ bpairs,
                                              const float* __restrict__ h32,
                                              uint4* __restrict__ hbA,
                                              uint4* __restrict__ hbB,
                                              uint2* __restrict__ hbC) {
    __shared__ int lc[NPB];
    int b = blockIdx.x, t = threadIdx.x;
    if (t < NPB) lc[t] = 0;
    __syncthreads();
    int start = b * CAP;
    int n = bptr[b] - start; if (n > CAP) n = CAP;
    for (int p = t; p < n; p += 256)
        atomicAdd(&lc[bpairs[start + p] & 127], 1);
    __syncthreads();
    int node = b * NPB + t;
    if (t < NPB && node < N_NODES) {
        float d = rsqrtf((float)(lc[t] + 1));   // +1 self loop
        const float* hp = h32 + (size_t)node * NC;
        float4 v0 = *(const float4*)(hp + 0);
        float4 v1 = *(const float4*)(hp + 4);
        float4 v2 = *(const float4*)(hp + 8);
        float4 v3 = *(const float4*)(hp + 12);
        float4 v4 = *(const float4*)(hp + 16);
        hbA[node] = make_uint4(bfpack(v0.x * d, v0.y * d), bfpack(v0.z * d, v0.w * d),
                               bfpack(v1.x * d, v1.y * d), bfpack(v1.z * d, v1.w * d));
        hbB[node] = make_uint4(bfpack(v2.x * d, v2.y * d), bfpack(v2.z * d, v2.w * d),
                               bfpack(v3.x * d, v3.y * d), bfpack(v3.z * d, v3.w * d));
        hbC[node] = make_uint2(bfpack(v4.x * d, v4.y * d), bfpack(v4.z * d, v4.w * d));
    }
}

// ---------- fused sort+reduce per 128-node bucket (R8-proven agg7, no dinv) ----------
__global__ __launch_bounds__(512) void k_agg7(const int* __restrict__ bptr,
                                              const int* __restrict__ bpairs,
                                              const uint4* __restrict__ hbA,
                                              const uint4* __restrict__ hbB,
                                              const uint2* __restrict__ hbC,
                                              const float* __restrict__ bmu,
                                              const float* __restrict__ bls,
                                              float* __restrict__ out) {
    __shared__ int lcnt[NPB];    // hist -> cursor
    __shared__ int lscan[NPB];   // inclusive scan
    __shared__ int sCnt[NPB];    // per-node count
    __shared__ int ssrc[CAP];    // node-sorted src ids
    int b = blockIdx.x, t = threadIdx.x;
    int start = b * CAP;
    int n = bptr[b] - start; if (n > CAP) n = CAP;

    if (t < NPB) lcnt[t] = 0;
    __syncthreads();
    for (int p = t; p < n; p += 512)
        atomicAdd(&lcnt[bpairs[start + p] & 127], 1);
    __syncthreads();

    int cnt = 0;
    if (t < NPB) { cnt = lcnt[t]; lscan[t] = cnt; sCnt[t] = cnt; }
    __syncthreads();
    for (int o = 1; o < NPB; o <<= 1) {
        int add = 0;
        if (t < NPB && t >= o) add = lscan[t - o];
        __syncthreads();
        if (t < NPB) lscan[t] += add;
        __syncthreads();
    }
    if (t < NPB) lcnt[t] = lscan[t] - cnt;   // cursor = exclusive
    __syncthreads();

    for (int p = t; p < n; p += 512) {
        int pk = bpairs[start + p];
        int q = atomicAdd(&lcnt[pk & 127], 1);
        ssrc[q] = ((unsigned)pk) >> 7;
    }
    __syncthreads();

    // reduce: 4 threads per node, quad edge-split, shuffle combine (xor 1,2)
    int nl = t >> 2, quarter = t & 3;
    int node = b * NPB + nl;
    int ccnt = sCnt[nl];
    int base = lscan[nl] - ccnt;
    int j0 = (ccnt * quarter) >> 2;
    int j1 = (ccnt * (quarter + 1)) >> 2;

    float a[NC];
#pragma unroll
    for (int c = 0; c < NC; c++) a[c] = 0.0f;

#define ADDROW(R)                                                        \
    {                                                                    \
        uint4 qa = hbA[(R)];                                             \
        uint4 qb = hbB[(R)];                                             \
        uint2 qc = hbC[(R)];                                             \
        a[0]  += bflo(qa.x); a[1]  += bfhi(qa.x);                        \
        a[2]  += bflo(qa.y); a[3]  += bfhi(qa.y);                        \
        a[4]  += bflo(qa.z); a[5]  += bfhi(qa.z);                        \
        a[6]  += bflo(qa.w); a[7]  += bfhi(qa.w);                        \
        a[8]  += bflo(qb.x); a[9]  += bfhi(qb.x);                        \
        a[10] += bflo(qb.y); a[11] += bfhi(qb.y);                        \
        a[12] += bflo(qb.z); a[13] += bfhi(qb.z);                        \
        a[14] += bflo(qb.w); a[15] += bfhi(qb.w);                        \
        a[16] += bflo(qc.x); a[17] += bfhi(qc.x);                        \
        a[18] += bflo(qc.y); a[19] += bfhi(qc.y);                        \
    }

    int j = j0;
    for (; j + 1 < j1; j += 2) {
        int r0 = ssrc[base + j];
        int r1 = ssrc[base + j + 1];
        ADDROW(r0);
        ADDROW(r1);
    }
    if (j < j1) {
        int r0 = ssrc[base + j];
        ADDROW(r0);
    }
    // self loop (h' already carries dinv[node]) on the quarter-0 thread
    if (quarter == 0 && node < N_NODES) ADDROW(node);
#undef ADDROW

#pragma unroll
    for (int c = 0; c < NC; c++) {
        a[c] += __shfl_xor(a[c], 1);
        a[c] += __shfl_xor(a[c], 2);
    }

    if (quarter == 0 && node < N_NODES) {
        float dn = rsqrtf((float)(ccnt + 1));
        float* om = out + (size_t)node * OC;
        float* ol = out + (size_t)N_NODES * OC + (size_t)node * OC;
#pragma unroll
        for (int c = 0; c < OC; c++) {
            om[c] = dn * a[c]      + bmu[c];
            ol[c] = dn * a[c + OC] + bls[c];
        }
    }
}

// ============ middle path (ws in [REQ, REQ2)): R8-proven serial pipeline ============
__global__ __launch_bounds__(1024) void k_bin3(const int* __restrict__ row,
                                               const int* __restrict__ col,
                                               int* __restrict__ bptr,
                                               int* __restrict__ bpairs) {
    __shared__ int   lh[NBUCK];
    __shared__ int   lscan[NBUCK];
    __shared__ int   gmino[NBUCK];
    __shared__ int   stage[CHUNK3];
    __shared__ unsigned short sbkt[CHUNK3];

    int t = threadIdx.x;
    int e0 = blockIdx.x * CHUNK3;
    int nE = N_EDGES - e0; if (nE > CHUNK3) nE = CHUNK3;
    int n4 = nE >> 2;
    const int4* c4 = (const int4*)(col + e0);
    const int4* r4 = (const int4*)(row + e0);

    for (int i = t; i < NBUCK; i += 1024) lh[i] = 0;
    __syncthreads();
    for (int j = t; j < n4; j += 1024) {
        int4 c = c4[j];
        atomicAdd(&lh[c.x >> 7], 1); atomicAdd(&lh[c.y >> 7], 1);
        atomicAdd(&lh[c.z >> 7], 1); atomicAdd(&lh[c.w >> 7], 1);
    }
    __syncthreads();
    int cnt = 0;
    if (t < NBUCK) { cnt = lh[t]; lscan[t] = cnt; }
    __syncthreads();
    for (int o = 1; o < NBUCK; o <<= 1) {
        int add = 0;
        if (t < NBUCK && t >= o) add = lscan[t - o];
        __syncthreads();
        if (t < NBUCK) lscan[t] += add;
        __syncthreads();
    }
    if (t < NBUCK) {
        int lofs = lscan[t] - cnt;
        int gbase = cnt ? atomicAdd(&bptr[t], cnt) : 0;
        gmino[t] = gbase - lofs;
        lh[t] = lofs;
    }
    __syncthreads();
    for (int j = t; j < n4; j += 1024) {
        int4 c = c4[j];
        int4 r = r4[j];
        int b0 = c.x >> 7, b1 = c.y >> 7, b2 = c.z >> 7, b3 = c.w >> 7;
        int s0 = atomicAdd(&lh[b0], 1);
        int s1 = atomicAdd(&lh[b1], 1);
        int s2 = atomicAdd(&lh[b2], 1);
        int s3 = atomicAdd(&lh[b3], 1);
        stage[s0] = (r.x << 7) | (c.x & 127); sbkt[s0] = (unsigned short)b0;
        stage[s1] = (r.y << 7) | (c.y & 127); sbkt[s1] = (unsigned short)b1;
        stage[s2] = (r.z << 7) | (c.z & 127); sbkt[s2] = (unsigned short)b2;
        stage[s3] = (r.w << 7) | (c.w & 127); sbkt[s3] = (unsigned short)b3;
    }
    __syncthreads();
    for (int j = t; j < nE; j += 1024) {
        int b = sbkt[j];
        int dst = gmino[b] + j;
        if (dst < (b + 1) * CAP) bpairs[dst] = stage[j];
    }
}

__global__ __launch_bounds__(256) void k_deg(const int* __restrict__ bptr,
                                             const int* __restrict__ bpairs,
                                             float* __restrict__ dinv) {
    __shared__ int lc[NPB];
    int b = blockIdx.x, t = threadIdx.x;
    if (t < NPB) lc[t] = 0;
    __syncthreads();
    int start = b * CAP;
    int n = bptr[b] - start; if (n > CAP) n = CAP;
    for (int p = t; p < n; p += 256)
        atomicAdd(&lc[bpairs[start + p] & 127], 1);
    __syncthreads();
    int node = b * NPB + t;
    if (t < NPB && node < N_NODES)
        dinv[node] = rsqrtf((float)(lc[t] + 1));
}

__global__ __launch_bounds__(256) void k_gemm6s(const float* __restrict__ x,
                                                const float* __restrict__ Wmu,
                                                const float* __restrict__ Wls,
                                                const float* __restrict__ dinv,
                                                uint4* __restrict__ hbA,
                                                uint4* __restrict__ hbB,
                                                uint2* __restrict__ hbC) {
    __shared__ float sW[NC * 272];
    int t = threadIdx.x;
    for (int idx = t; idx < IN_CH * OC; idx += 256) {
        int k = idx / OC, c = idx - (idx / OC) * OC;
        int kk = k >> 6, j = k & 63;
        sW[c * 272 + kk * 68 + j]          = Wmu[idx];
        sW[(c + OC) * 272 + kk * 68 + j]   = Wls[idx];
    }
    __syncthreads();

    int kk = t & 3;
    int slot = t >> 2;
    int n0 = blockIdx.x * 128 + slot;

    int nd[2];
#pragma unroll
    for (int u = 0; u < 2; u++) {
        int n = n0 + u * 64;
        nd[u] = (n < N_NODES) ? n : (N_NODES - 1);
    }

    float acc[2][NC];
#pragma unroll
    for (int u = 0; u < 2; u++)
#pragma unroll
        for (int c = 0; c < NC; c++) acc[u][c] = 0.0f;

    const float4* x4 = (const float4*)x;

#pragma unroll 4
    for (int j4 = 0; j4 < 16; j4++) {
        float4 xv0 = x4[(size_t)nd[0] * 64 + kk * 16 + j4];
        float4 xv1 = x4[(size_t)nd[1] * 64 + kk * 16 + j4];
#pragma unroll
        for (int c = 0; c < NC; c++) {
            float4 w = *(const float4*)&sW[c * 272 + kk * 68 + j4 * 4];
            acc[0][c] += xv0.x * w.x + xv0.y * w.y + xv0.z * w.z + xv0.w * w.w;
            acc[1][c] += xv1.x * w.x + xv1.y * w.y + xv1.z * w.z + xv1.w * w.w;
        }
    }

#pragma unroll
    for (int u = 0; u < 2; u++)
#pragma unroll
        for (int c = 0; c < NC; c++) {
            acc[u][c] += __shfl_xor(acc[u][c], 2);
            acc[u][c] += __shfl_xor(acc[u][c], 1);
        }

    if (kk == 0) {
#pragma unroll
        for (int u = 0; u < 2; u++) {
            int n = n0 + u * 64;
            if (n >= N_NODES) continue;
            float d = dinv[n];
            hbA[n] = make_uint4(bfpack(acc[u][0] * d,  acc[u][1] * d),
                                bfpack(acc[u][2] * d,  acc[u][3] * d),
                                bfpack(acc[u][4] * d,  acc[u][5] * d),
                                bfpack(acc[u][6] * d,  acc[u][7] * d));
            hbB[n] = make_uint4(bfpack(acc[u][8] * d,  acc[u][9] * d),
                                bfpack(acc[u][10] * d, acc[u][11] * d),
                                bfpack(acc[u][12] * d, acc[u][13] * d),
                                bfpack(acc[u][14] * d, acc[u][15] * d));
            hbC[n] = make_uint2(bfpack(acc[u][16] * d, acc[u][17] * d),
                                bfpack(acc[u][18] * d, acc[u][19] * d));
        }
    }
}

// ======================= fallback (atomic scatter path, tiny ws) =======================
__global__ __launch_bounds__(256) void k_init_deg(float* __restrict__ deg) {
    int i = blockIdx.x * 256 + threadIdx.x;
    if (i < N_NODES) deg[i] = 1.0f;
}
__global__ __launch_bounds__(256) void k_count(const int* __restrict__ col, float* __restrict__ deg) {
    int e = blockIdx.x * 256 + threadIdx.x;
    if (e < N_EDGES) atomicAdd(&deg[col[e]], 1.0f);
}
__global__ __launch_bounds__(256) void k_dinvk(float* __restrict__ deg) {
    int i = blockIdx.x * 256 + threadIdx.x;
    if (i < N_NODES) deg[i] = rsqrtf(deg[i]);
}
__global__ __launch_bounds__(256) void k_gemm_f32(const float* __restrict__ x,
                                                  const float* __restrict__ Wmu,
                                                  const float* __restrict__ Wls,
                                                  float* __restrict__ h) {
    int node = blockIdx.x * 256 + threadIdx.x;
    if (node >= N_NODES) return;
    const float4* x4 = (const float4*)(x + (size_t)node * IN_CH);
    float acc[NC];
#pragma unroll
    for (int c = 0; c < NC; c++) acc[c] = 0.0f;
    for (int k4 = 0; k4 < IN_CH / 4; k4++) {
        float4 xv = x4[k4];
        float xk[4] = {xv.x, xv.y, xv.z, xv.w};
#pragma unroll
        for (int kk = 0; kk < 4; kk++) {
            const float* wm = Wmu + (k4 * 4 + kk) * OC;
            const float* wl = Wls + (k4 * 4 + kk) * OC;
#pragma unroll
            for (int c = 0; c < OC; c++) {
                acc[c]      += xk[kk] * wm[c];
                acc[c + OC] += xk[kk] * wl[c];
            }
        }
    }
    float* hp = h + (size_t)node * NC;
#pragma unroll
    for (int c = 0; c < NC; c++) hp[c] = acc[c];
}
__global__ __launch_bounds__(256) void k_scatter(const int* __restrict__ row, const int* __restrict__ col,
                                                 const float* __restrict__ dinv, const float* __restrict__ h,
                                                 float* __restrict__ out) {
    int e = blockIdx.x * 256 + threadIdx.x;
    if (e >= N_EDGES) return;
    int r = row[e], c = col[e];
    float s = dinv[r] * dinv[c];
    const float* hp = h + (size_t)r * NC;
    float* om = out + (size_t)c * OC;
    float* ol = om + (size_t)N_NODES * OC;
#pragma unroll
    for (int k = 0; k < OC; k++) atomicAdd(om + k, hp[k] * s);
#pragma unroll
    for (int k = 0; k < OC; k++) atomicAdd(ol + k, hp[OC + k] * s);
}
__global__ __launch_bounds__(256) void k_final(const float* __restrict__ h, const float* __restrict__ dinv,
                                               const float* __restrict__ bmu, const float* __restrict__ bls,
                                               float* __restrict__ out) {
    int i = blockIdx.x * 256 + threadIdx.x;
    if (i >= N_NODES * OC) return;
    int node = i / OC, c = i - node * OC;
    float d = dinv[node];
    float d2 = d * d;
    out[i]                += h[node * NC + c]      * d2 + bmu[c];
    out[N_NODES * OC + i] += h[node * NC + OC + c] * d2 + bls[c];
}

extern "C" void kernel_launch(void* const* d_in, const int* in_sizes, int n_in,
                              void* d_out, int out_size, void* d_ws, size_t ws_size,
                              hipStream_t stream) {
    const float* x   = (const float*)d_in[0];
    const int*   ei  = (const int*)d_in[1];
    const float* Wmu = (const float*)d_in[2];
    const float* bmu = (const float*)d_in[3];
    const float* Wls = (const float*)d_in[4];
    const float* bls = (const float*)d_in[5];
    float* out = (float*)d_out;

    const int* row = ei;            // edge_index[0] (sources)
    const int* col = ei + N_EDGES;  // edge_index[1] (targets)

    // ws layout:
    //   bptr   int[NBUCK]       @ 0        (3.1 KB)
    //   dinv   f32[100096]      @ 8 KB     (400 KB, middle path only)
    //   hbA    uint4[100000]    @ 512 KB   (1.6 MB)  \
    //   hbB    uint4[100000]    @ +1.6 MB  (1.6 MB)   } SoA bf16 prescaled h (4 MB)
    //   hbC    uint2[100000]    @ +3.2 MB  (0.8 MB)  /
    //   bpairs int[NBUCK*CAP]   @ 4.5 MB   (15.2 MB)
    //   h32    f32[100000*20]   @ 20 MB    (8 MB, fast path only)
    const size_t BPAIRS_OFF = (size_t)(9 << 19);   // 4.5 MiB
    const size_t REQ  = BPAIRS_OFF + (size_t)NBUCK * CAP * 4;      // ~19.0 MiB
    const size_t H32_OFF = (size_t)20 << 20;                       // 20 MiB
    const size_t REQ2 = H32_OFF + (size_t)N_NODES * NC * 4;        // ~27.6 MiB

    if (ws_size >= REQ2) {
        char* w = (char*)d_ws;
        int*      bptr   = (int*)(w);
        uint4*    hbA    = (uint4*)(w + (512 << 10));
        uint4*    hbB    = (uint4*)(w + (512 << 10) + 1600000);
        uint2*    hbC    = (uint2*)(w + (512 << 10) + 3200000);
        int*      bpairs = (int*)(w + BPAIRS_OFF);
        float*    h32    = (float*)(w + H32_OFF);

        k_initptr<<<(NBUCK + 255) / 256, 256, 0, stream>>>(bptr);
        k_mega32<<<NMEGA, 1024, 0, stream>>>(row, col, bptr, bpairs, x, Wmu, Wls, h32);
        k_degs<<<NBUCK, 256, 0, stream>>>(bptr, bpairs, h32, hbA, hbB, hbC);
        k_agg7<<<NBUCK, 512, 0, stream>>>(bptr, bpairs, hbA, hbB, hbC, bmu, bls, out);
    } else if (ws_size >= REQ) {
        char* w = (char*)d_ws;
        int*      bptr   = (int*)(w);
        float*    dinv   = (float*)(w + 8192);
        uint4*    hbA    = (uint4*)(w + (512 << 10));
        uint4*    hbB    = (uint4*)(w + (512 << 10) + 1600000);
        uint2*    hbC    = (uint2*)(w + (512 << 10) + 3200000);
        int*      bpairs = (int*)(w + BPAIRS_OFF);

        k_initptr<<<(NBUCK + 255) / 256, 256, 0, stream>>>(bptr);
        k_bin3<<<NCHUNK3, 1024, 0, stream>>>(row, col, bptr, bpairs);
        k_deg<<<NBUCK, 256, 0, stream>>>(bptr, bpairs, dinv);
        k_gemm6s<<<(N_NODES + 127) / 128, 256, 0, stream>>>(x, Wmu, Wls, dinv, hbA, hbB, hbC);
        k_agg7<<<NBUCK, 512, 0, stream>>>(bptr, bpairs, hbA, hbB, hbC, bmu, bls, out);
    } else {
        float* deg = (float*)d_ws;
        float* h   = (float*)((char*)d_ws + (1 << 20));
        hipMemsetAsync(d_out, 0, (size_t)out_size * sizeof(float), stream);
        k_init_deg<<<(N_NODES + 255) / 256, 256, 0, stream>>>(deg);
        k_count<<<(N_EDGES + 255) / 256, 256, 0, stream>>>(col, deg);
        k_dinvk<<<(N_NODES + 255) / 256, 256, 0, stream>>>(deg);
        k_gemm_f32<<<(N_NODES + 255) / 256, 256, 0, stream>>>(x, Wmu, Wls, h);
        k_scatter<<<(N_EDGES + 255) / 256, 256, 0, stream>>>(row, col, deg, h, out);
        k_final<<<(N_NODES * OC + 255) / 256, 256, 0, stream>>>(h, deg, bmu, bls, out);
    }
}

// Round 11
// 274.782 us; speedup vs baseline: 1.1277x; 1.0823x over previous
//
#include <hip/hip_runtime.h>
#include <math.h>

#define N_NODES 100000
#define N_EDGES 3200000
#define IN_CH 256
#define NC 20        // combined output channels (10 mu + 10 logstd)
#define OC 10
#define NPB 128      // nodes per bucket (col >> 7)
#define NBUCK 782    // ceil(100000/128)
#define CAP 4864     // per-bucket capacity: mean 4096, sigma ~64 -> +12 sigma

// binning geometry: LDS counting sort, coalesced flush
#define CHUNK3 8192          // edges per bin-role block
#define NCHUNK3 391          // ceil(3.2M/8192)
#define NGEMMB 196           // ceil(100000/512) gemm-role blocks (512 nodes each)
#define NMEGA 587            // NCHUNK3 + NGEMMB

// ---------- init per-bucket allocation cursors ----------
__global__ __launch_bounds__(256) void k_initptr(int* __restrict__ bptr) {
    int i = blockIdx.x * 256 + threadIdx.x;
    if (i < NBUCK) bptr[i] = i * CAP;
}

// ---------- bf16 pack helpers (RNE) ----------
__device__ __forceinline__ unsigned bfpack(float a, float b) {
    unsigned ua = __float_as_uint(a), ub = __float_as_uint(b);
    ua = (ua + 0x7FFFu + ((ua >> 16) & 1u)) >> 16;
    ub = (ub + 0x7FFFu + ((ub >> 16) & 1u)) >> 16;
    return ua | (ub << 16);
}
__device__ __forceinline__ float bflo(unsigned p) { return __uint_as_float(p << 16); }
__device__ __forceinline__ float bfhi(unsigned p) { return __uint_as_float(p & 0xFFFF0000u); }

// ---------- LDS overlays for the two mega roles ----------
struct BinSmem {
    int lh[NBUCK];       // counts -> scatter cursor
    int lscan[NBUCK];    // inclusive scan
    int gmino[NBUCK];    // gbase - lofs
    int stage[CHUNK3];   // bucket-sorted packed pairs
    unsigned short sbkt[CHUNK3];
};
struct GemmSmem { float sW[NC * 272]; };
union MegaSmem { BinSmem b; GemmSmem g; };

// ---------- MEGA (R9/R10-proven overlap): bin + gemm co-resident; fp32 h out ----------
__global__ __launch_bounds__(1024) void k_mega32(const int* __restrict__ row,
                                                 const int* __restrict__ col,
                                                 int* __restrict__ bptr,
                                                 int* __restrict__ bpairs,
                                                 const float* __restrict__ x,
                                                 const float* __restrict__ Wmu,
                                                 const float* __restrict__ Wls,
                                                 float* __restrict__ h32) {
    __shared__ MegaSmem sm;
    int bid = blockIdx.x;
    int t = threadIdx.x;
    bool isGemm = (bid < 2 * NGEMMB) && (bid & 1);

    if (!isGemm) {
        // ================= bin role (verbatim bin3 logic) =================
        int cb = (bid < 2 * NGEMMB) ? (bid >> 1) : (bid - NGEMMB);
        int e0 = cb * CHUNK3;
        int nE = N_EDGES - e0; if (nE > CHUNK3) nE = CHUNK3;
        int n4 = nE >> 2;
        const int4* c4 = (const int4*)(col + e0);
        const int4* r4 = (const int4*)(row + e0);

        for (int i = t; i < NBUCK; i += 1024) sm.b.lh[i] = 0;
        __syncthreads();

        for (int j = t; j < n4; j += 1024) {
            int4 c = c4[j];
            atomicAdd(&sm.b.lh[c.x >> 7], 1); atomicAdd(&sm.b.lh[c.y >> 7], 1);
            atomicAdd(&sm.b.lh[c.z >> 7], 1); atomicAdd(&sm.b.lh[c.w >> 7], 1);
        }
        __syncthreads();

        int cnt = 0;
        if (t < NBUCK) { cnt = sm.b.lh[t]; sm.b.lscan[t] = cnt; }
        __syncthreads();
        for (int o = 1; o < NBUCK; o <<= 1) {
            int add = 0;
            if (t < NBUCK && t >= o) add = sm.b.lscan[t - o];
            __syncthreads();
            if (t < NBUCK) sm.b.lscan[t] += add;
            __syncthreads();
        }
        if (t < NBUCK) {
            int lofs = sm.b.lscan[t] - cnt;
            int gbase = cnt ? atomicAdd(&bptr[t], cnt) : 0;
            sm.b.gmino[t] = gbase - lofs;
            sm.b.lh[t] = lofs;
        }
        __syncthreads();

        for (int j = t; j < n4; j += 1024) {
            int4 c = c4[j];
            int4 r = r4[j];
            int b0 = c.x >> 7, b1 = c.y >> 7, b2 = c.z >> 7, b3 = c.w >> 7;
            int s0 = atomicAdd(&sm.b.lh[b0], 1);
            int s1 = atomicAdd(&sm.b.lh[b1], 1);
            int s2 = atomicAdd(&sm.b.lh[b2], 1);
            int s3 = atomicAdd(&sm.b.lh[b3], 1);
            sm.b.stage[s0] = (r.x << 7) | (c.x & 127); sm.b.sbkt[s0] = (unsigned short)b0;
            sm.b.stage[s1] = (r.y << 7) | (c.y & 127); sm.b.sbkt[s1] = (unsigned short)b1;
            sm.b.stage[s2] = (r.z << 7) | (c.z & 127); sm.b.sbkt[s2] = (unsigned short)b2;
            sm.b.stage[s3] = (r.w << 7) | (c.w & 127); sm.b.sbkt[s3] = (unsigned short)b3;
        }
        __syncthreads();

        for (int j = t; j < nE; j += 1024) {
            int b = sm.b.sbkt[j];
            int dst = sm.b.gmino[b] + j;
            if (dst < (b + 1) * CAP) bpairs[dst] = sm.b.stage[j];
        }
    } else {
        // ================= gemm role (verbatim compute; fp32 h store) ================
        // unroll-4 keeps the 4 loads of each 64B x-line consecutive (R5 lesson).
        int gb = bid >> 1;
        for (int idx = t; idx < IN_CH * OC; idx += 1024) {
            int k = idx / OC, c = idx - (idx / OC) * OC;
            int kk = k >> 6, j = k & 63;
            sm.g.sW[c * 272 + kk * 68 + j]        = Wmu[idx];
            sm.g.sW[(c + OC) * 272 + kk * 68 + j] = Wls[idx];
        }
        __syncthreads();

        int kk = t & 3;
        int slot = t >> 2;                       // 0..255
        int n0 = gb * 512 + slot;                // thread's nodes: n0, n0+256

        int nd[2];
#pragma unroll
        for (int u = 0; u < 2; u++) {
            int n = n0 + u * 256;
            nd[u] = (n < N_NODES) ? n : (N_NODES - 1);
        }

        float acc[2][NC];
#pragma unroll
        for (int u = 0; u < 2; u++)
#pragma unroll
            for (int c = 0; c < NC; c++) acc[u][c] = 0.0f;

        const float4* x4 = (const float4*)x;

#pragma unroll 4
        for (int j4 = 0; j4 < 16; j4++) {
            float4 xv0 = x4[(size_t)nd[0] * 64 + kk * 16 + j4];
            float4 xv1 = x4[(size_t)nd[1] * 64 + kk * 16 + j4];
#pragma unroll
            for (int c = 0; c < NC; c++) {
                float4 w = *(const float4*)&sm.g.sW[c * 272 + kk * 68 + j4 * 4];
                acc[0][c] += xv0.x * w.x + xv0.y * w.y + xv0.z * w.z + xv0.w * w.w;
                acc[1][c] += xv1.x * w.x + xv1.y * w.y + xv1.z * w.z + xv1.w * w.w;
            }
        }

#pragma unroll
        for (int u = 0; u < 2; u++)
#pragma unroll
            for (int c = 0; c < NC; c++) {
                acc[u][c] += __shfl_xor(acc[u][c], 2);
                acc[u][c] += __shfl_xor(acc[u][c], 1);
            }

        if (kk == 0) {
#pragma unroll
            for (int u = 0; u < 2; u++) {
                int n = n0 + u * 256;
                if (n >= N_NODES) continue;
                float* hp = h32 + (size_t)n * NC;
                *(float4*)(hp + 0)  = make_float4(acc[u][0],  acc[u][1],  acc[u][2],  acc[u][3]);
                *(float4*)(hp + 4)  = make_float4(acc[u][4],  acc[u][5],  acc[u][6],  acc[u][7]);
                *(float4*)(hp + 8)  = make_float4(acc[u][8],  acc[u][9],  acc[u][10], acc[u][11]);
                *(float4*)(hp + 12) = make_float4(acc[u][12], acc[u][13], acc[u][14], acc[u][15]);
                *(float4*)(hp + 16) = make_float4(acc[u][16], acc[u][17], acc[u][18], acc[u][19]);
            }
        }
    }
}

// ---------- degree count + node-space scale/pack: fp32 h -> AoS prescaled bf16 ----------
// AoS (40B rows) proven better than SoA for the gather phase (R4 262 vs R8 283).
__global__ __launch_bounds__(256) void k_degs_aos(const int* __restrict__ bptr,
                                                  const int* __restrict__ bpairs,
                                                  const float* __restrict__ h32,
                                                  unsigned* __restrict__ hbf) {
    __shared__ int lc[NPB];
    int b = blockIdx.x, t = threadIdx.x;
    if (t < NPB) lc[t] = 0;
    __syncthreads();
    int start = b * CAP;
    int n = bptr[b] - start; if (n > CAP) n = CAP;
    for (int p = t; p < n; p += 256)
        atomicAdd(&lc[bpairs[start + p] & 127], 1);
    __syncthreads();
    int node = b * NPB + t;
    if (t < NPB && node < N_NODES) {
        float d = rsqrtf((float)(lc[t] + 1));   // +1 self loop
        const float* hp = h32 + (size_t)node * NC;
        float4 v0 = *(const float4*)(hp + 0);
        float4 v1 = *(const float4*)(hp + 4);
        float4 v2 = *(const float4*)(hp + 8);
        float4 v3 = *(const float4*)(hp + 12);
        float4 v4 = *(const float4*)(hp + 16);
        unsigned* op = hbf + (size_t)node * 10;
        *(uint2*)(op + 0) = make_uint2(bfpack(v0.x * d, v0.y * d), bfpack(v0.z * d, v0.w * d));
        *(uint2*)(op + 2) = make_uint2(bfpack(v1.x * d, v1.y * d), bfpack(v1.z * d, v1.w * d));
        *(uint2*)(op + 4) = make_uint2(bfpack(v2.x * d, v2.y * d), bfpack(v2.z * d, v2.w * d));
        *(uint2*)(op + 6) = make_uint2(bfpack(v3.x * d, v3.y * d), bfpack(v3.z * d, v3.w * d));
        *(uint2*)(op + 8) = make_uint2(bfpack(v4.x * d, v4.y * d), bfpack(v4.z * d, v4.w * d));
    }
}

// ---------- fused sort+reduce per 128-node bucket (R4-proven agg4, AoS gathers) ----------
__global__ __launch_bounds__(256) void k_agg4(const int* __restrict__ bptr,
                                              const int* __restrict__ bpairs,
                                              const unsigned* __restrict__ hbf,
                                              const float* __restrict__ bmu,
                                              const float* __restrict__ bls,
                                              float* __restrict__ out) {
    __shared__ int lcnt[NPB];    // hist -> cursor
    __shared__ int lscan[NPB];   // inclusive scan
    __shared__ int sCnt[NPB];    // per-node count
    __shared__ int ssrc[CAP];    // node-sorted src ids
    int b = blockIdx.x, t = threadIdx.x;
    int start = b * CAP;
    int n = bptr[b] - start; if (n > CAP) n = CAP;

    if (t < NPB) lcnt[t] = 0;
    __syncthreads();
    for (int p = t; p < n; p += 256)
        atomicAdd(&lcnt[bpairs[start + p] & 127], 1);
    __syncthreads();

    int cnt = 0;
    if (t < NPB) { cnt = lcnt[t]; lscan[t] = cnt; sCnt[t] = cnt; }
    __syncthreads();
    for (int o = 1; o < NPB; o <<= 1) {
        int add = 0;
        if (t < NPB && t >= o) add = lscan[t - o];
        __syncthreads();
        if (t < NPB) lscan[t] += add;
        __syncthreads();
    }
    if (t < NPB) lcnt[t] = lscan[t] - cnt;   // cursor = exclusive
    __syncthreads();

    for (int p = t; p < n; p += 256) {
        int pk = bpairs[start + p];
        int q = atomicAdd(&lcnt[pk & 127], 1);
        ssrc[q] = ((unsigned)pk) >> 7;
    }
    __syncthreads();

    // reduce: 2 threads per node, edge-split halves, shuffle combine
    int nl = t >> 1, half = t & 1;
    int node = b * NPB + nl;
    int ccnt = sCnt[nl];
    int base = lscan[nl] - ccnt;
    int mid = ccnt >> 1;
    int j0 = half ? mid : 0;
    int j1 = half ? ccnt : mid;

    float a[NC];
#pragma unroll
    for (int c = 0; c < NC; c++) a[c] = 0.0f;

#define ADDROW(R)                                                        \
    {                                                                    \
        const unsigned* hp_ = hbf + (size_t)(R) * 10;                    \
        uint2 q0 = *(const uint2*)(hp_ + 0);                             \
        uint2 q1 = *(const uint2*)(hp_ + 2);                             \
        uint2 q2 = *(const uint2*)(hp_ + 4);                             \
        uint2 q3 = *(const uint2*)(hp_ + 6);                             \
        uint2 q4 = *(const uint2*)(hp_ + 8);                             \
        a[0]  += bflo(q0.x); a[1]  += bfhi(q0.x);                        \
        a[2]  += bflo(q0.y); a[3]  += bfhi(q0.y);                        \
        a[4]  += bflo(q1.x); a[5]  += bfhi(q1.x);                        \
        a[6]  += bflo(q1.y); a[7]  += bfhi(q1.y);                        \
        a[8]  += bflo(q2.x); a[9]  += bfhi(q2.x);                        \
        a[10] += bflo(q2.y); a[11] += bfhi(q2.y);                        \
        a[12] += bflo(q3.x); a[13] += bfhi(q3.x);                        \
        a[14] += bflo(q3.y); a[15] += bfhi(q3.y);                        \
        a[16] += bflo(q4.x); a[17] += bfhi(q4.x);                        \
        a[18] += bflo(q4.y); a[19] += bfhi(q4.y);                        \
    }

    int j = j0;
    for (; j + 1 < j1; j += 2) {
        int r0 = ssrc[base + j];
        int r1 = ssrc[base + j + 1];
        ADDROW(r0);
        ADDROW(r1);
    }
    if (j < j1) {
        int r0 = ssrc[base + j];
        ADDROW(r0);
    }
    // self loop (h' already carries dinv[node]) on the even-half thread
    if (half == 0 && node < N_NODES) ADDROW(node);
#undef ADDROW

#pragma unroll
    for (int c = 0; c < NC; c++) a[c] += __shfl_xor(a[c], 1);

    if (half == 0 && node < N_NODES) {
        float dn = rsqrtf((float)(ccnt + 1));
        float* om = out + (size_t)node * OC;
        float* ol = out + (size_t)N_NODES * OC + (size_t)node * OC;
#pragma unroll
        for (int c = 0; c < OC; c++) {
            om[c] = dn * a[c]      + bmu[c];
            ol[c] = dn * a[c + OC] + bls[c];
        }
    }
}

// ============ middle path (ws in [REQ, REQ2)): R4-exact 262us serial pipeline ============
__global__ __launch_bounds__(1024) void k_bin3(const int* __restrict__ row,
                                               const int* __restrict__ col,
                                               int* __restrict__ bptr,
                                               int* __restrict__ bpairs) {
    __shared__ int   lh[NBUCK];
    __shared__ int   lscan[NBUCK];
    __shared__ int   gmino[NBUCK];
    __shared__ int   stage[CHUNK3];
    __shared__ unsigned short sbkt[CHUNK3];

    int t = threadIdx.x;
    int e0 = blockIdx.x * CHUNK3;
    int nE = N_EDGES - e0; if (nE > CHUNK3) nE = CHUNK3;
    int n4 = nE >> 2;
    const int4* c4 = (const int4*)(col + e0);
    const int4* r4 = (const int4*)(row + e0);

    for (int i = t; i < NBUCK; i += 1024) lh[i] = 0;
    __syncthreads();
    for (int j = t; j < n4; j += 1024) {
        int4 c = c4[j];
        atomicAdd(&lh[c.x >> 7], 1); atomicAdd(&lh[c.y >> 7], 1);
        atomicAdd(&lh[c.z >> 7], 1); atomicAdd(&lh[c.w >> 7], 1);
    }
    __syncthreads();
    int cnt = 0;
    if (t < NBUCK) { cnt = lh[t]; lscan[t] = cnt; }
    __syncthreads();
    for (int o = 1; o < NBUCK; o <<= 1) {
        int add = 0;
        if (t < NBUCK && t >= o) add = lscan[t - o];
        __syncthreads();
        if (t < NBUCK) lscan[t] += add;
        __syncthreads();
    }
    if (t < NBUCK) {
        int lofs = lscan[t] - cnt;
        int gbase = cnt ? atomicAdd(&bptr[t], cnt) : 0;
        gmino[t] = gbase - lofs;
        lh[t] = lofs;
    }
    __syncthreads();
    for (int j = t; j < n4; j += 1024) {
        int4 c = c4[j];
        int4 r = r4[j];
        int b0 = c.x >> 7, b1 = c.y >> 7, b2 = c.z >> 7, b3 = c.w >> 7;
        int s0 = atomicAdd(&lh[b0], 1);
        int s1 = atomicAdd(&lh[b1], 1);
        int s2 = atomicAdd(&lh[b2], 1);
        int s3 = atomicAdd(&lh[b3], 1);
        stage[s0] = (r.x << 7) | (c.x & 127); sbkt[s0] = (unsigned short)b0;
        stage[s1] = (r.y << 7) | (c.y & 127); sbkt[s1] = (unsigned short)b1;
        stage[s2] = (r.z << 7) | (c.z & 127); sbkt[s2] = (unsigned short)b2;
        stage[s3] = (r.w << 7) | (c.w & 127); sbkt[s3] = (unsigned short)b3;
    }
    __syncthreads();
    for (int j = t; j < nE; j += 1024) {
        int b = sbkt[j];
        int dst = gmino[b] + j;
        if (dst < (b + 1) * CAP) bpairs[dst] = stage[j];
    }
}

__global__ __launch_bounds__(256) void k_deg(const int* __restrict__ bptr,
                                             const int* __restrict__ bpairs,
                                             float* __restrict__ dinv) {
    __shared__ int lc[NPB];
    int b = blockIdx.x, t = threadIdx.x;
    if (t < NPB) lc[t] = 0;
    __syncthreads();
    int start = b * CAP;
    int n = bptr[b] - start; if (n > CAP) n = CAP;
    for (int p = t; p < n; p += 256)
        atomicAdd(&lc[bpairs[start + p] & 127], 1);
    __syncthreads();
    int node = b * NPB + t;
    if (t < NPB && node < N_NODES)
        dinv[node] = rsqrtf((float)(lc[t] + 1));
}

__global__ __launch_bounds__(256) void k_gemm6(const float* __restrict__ x,
                                               const float* __restrict__ Wmu,
                                               const float* __restrict__ Wls,
                                               const float* __restrict__ dinv,
                                               unsigned* __restrict__ hbf) {
    __shared__ float sW[NC * 272];
    int t = threadIdx.x;
    for (int idx = t; idx < IN_CH * OC; idx += 256) {
        int k = idx / OC, c = idx - (idx / OC) * OC;
        int kk = k >> 6, j = k & 63;
        sW[c * 272 + kk * 68 + j]          = Wmu[idx];
        sW[(c + OC) * 272 + kk * 68 + j]   = Wls[idx];
    }
    __syncthreads();

    int kk = t & 3;
    int slot = t >> 2;
    int n0 = blockIdx.x * 128 + slot;

    int nd[2];
#pragma unroll
    for (int u = 0; u < 2; u++) {
        int n = n0 + u * 64;
        nd[u] = (n < N_NODES) ? n : (N_NODES - 1);
    }

    float acc[2][NC];
#pragma unroll
    for (int u = 0; u < 2; u++)
#pragma unroll
        for (int c = 0; c < NC; c++) acc[u][c] = 0.0f;

    const float4* x4 = (const float4*)x;

#pragma unroll 4
    for (int j4 = 0; j4 < 16; j4++) {
        float4 xv0 = x4[(size_t)nd[0] * 64 + kk * 16 + j4];
        float4 xv1 = x4[(size_t)nd[1] * 64 + kk * 16 + j4];
#pragma unroll
        for (int c = 0; c < NC; c++) {
            float4 w = *(const float4*)&sW[c * 272 + kk * 68 + j4 * 4];
            acc[0][c] += xv0.x * w.x + xv0.y * w.y + xv0.z * w.z + xv0.w * w.w;
            acc[1][c] += xv1.x * w.x + xv1.y * w.y + xv1.z * w.z + xv1.w * w.w;
        }
    }

#pragma unroll
    for (int u = 0; u < 2; u++)
#pragma unroll
        for (int c = 0; c < NC; c++) {
            acc[u][c] += __shfl_xor(acc[u][c], 2);
            acc[u][c] += __shfl_xor(acc[u][c], 1);
        }

    if (kk == 0) {
#pragma unroll
        for (int u = 0; u < 2; u++) {
            int n = n0 + u * 64;
            if (n >= N_NODES) continue;
            float d = dinv[n];
            unsigned* hp = hbf + (size_t)n * 10;
            *(uint2*)(hp + 0) = make_uint2(bfpack(acc[u][0] * d,  acc[u][1] * d),
                                           bfpack(acc[u][2] * d,  acc[u][3] * d));
            *(uint2*)(hp + 2) = make_uint2(bfpack(acc[u][4] * d,  acc[u][5] * d),
                                           bfpack(acc[u][6] * d,  acc[u][7] * d));
            *(uint2*)(hp + 4) = make_uint2(bfpack(acc[u][8] * d,  acc[u][9] * d),
                                           bfpack(acc[u][10] * d, acc[u][11] * d));
            *(uint2*)(hp + 6) = make_uint2(bfpack(acc[u][12] * d, acc[u][13] * d),
                                           bfpack(acc[u][14] * d, acc[u][15] * d));
            *(uint2*)(hp + 8) = make_uint2(bfpack(acc[u][16] * d, acc[u][17] * d),
                                           bfpack(acc[u][18] * d, acc[u][19] * d));
        }
    }
}

// ======================= fallback (atomic scatter path, tiny ws) =======================
__global__ __launch_bounds__(256) void k_init_deg(float* __restrict__ deg) {
    int i = blockIdx.x * 256 + threadIdx.x;
    if (i < N_NODES) deg[i] = 1.0f;
}
__global__ __launch_bounds__(256) void k_count(const int* __restrict__ col, float* __restrict__ deg) {
    int e = blockIdx.x * 256 + threadIdx.x;
    if (e < N_EDGES) atomicAdd(&deg[col[e]], 1.0f);
}
__global__ __launch_bounds__(256) void k_dinvk(float* __restrict__ deg) {
    int i = blockIdx.x * 256 + threadIdx.x;
    if (i < N_NODES) deg[i] = rsqrtf(deg[i]);
}
__global__ __launch_bounds__(256) void k_gemm_f32(const float* __restrict__ x,
                                                  const float* __restrict__ Wmu,
                                                  const float* __restrict__ Wls,
                                                  float* __restrict__ h) {
    int node = blockIdx.x * 256 + threadIdx.x;
    if (node >= N_NODES) return;
    const float4* x4 = (const float4*)(x + (size_t)node * IN_CH);
    float acc[NC];
#pragma unroll
    for (int c = 0; c < NC; c++) acc[c] = 0.0f;
    for (int k4 = 0; k4 < IN_CH / 4; k4++) {
        float4 xv = x4[k4];
        float xk[4] = {xv.x, xv.y, xv.z, xv.w};
#pragma unroll
        for (int kk = 0; kk < 4; kk++) {
            const float* wm = Wmu + (k4 * 4 + kk) * OC;
            const float* wl = Wls + (k4 * 4 + kk) * OC;
#pragma unroll
            for (int c = 0; c < OC; c++) {
                acc[c]      += xk[kk] * wm[c];
                acc[c + OC] += xk[kk] * wl[c];
            }
        }
    }
    float* hp = h + (size_t)node * NC;
#pragma unroll
    for (int c = 0; c < NC; c++) hp[c] = acc[c];
}
__global__ __launch_bounds__(256) void k_scatter(const int* __restrict__ row, const int* __restrict__ col,
                                                 const float* __restrict__ dinv, const float* __restrict__ h,
                                                 float* __restrict__ out) {
    int e = blockIdx.x * 256 + threadIdx.x;
    if (e >= N_EDGES) return;
    int r = row[e], c = col[e];
    float s = dinv[r] * dinv[c];
    const float* hp = h + (size_t)r * NC;
    float* om = out + (size_t)c * OC;
    float* ol = om + (size_t)N_NODES * OC;
#pragma unroll
    for (int k = 0; k < OC; k++) atomicAdd(om + k, hp[k] * s);
#pragma unroll
    for (int k = 0; k < OC; k++) atomicAdd(ol + k, hp[OC + k] * s);
}
__global__ __launch_bounds__(256) void k_final(const float* __restrict__ h, const float* __restrict__ dinv,
                                               const float* __restrict__ bmu, const float* __restrict__ bls,
                                               float* __restrict__ out) {
    int i = blockIdx.x * 256 + threadIdx.x;
    if (i >= N_NODES * OC) return;
    int node = i / OC, c = i - node * OC;
    float d = dinv[node];
    float d2 = d * d;
    out[i]                += h[node * NC + c]      * d2 + bmu[c];
    out[N_NODES * OC + i] += h[node * NC + OC + c] * d2 + bls[c];
}

extern "C" void kernel_launch(void* const* d_in, const int* in_sizes, int n_in,
                              void* d_out, int out_size, void* d_ws, size_t ws_size,
                              hipStream_t stream) {
    const float* x   = (const float*)d_in[0];
    const int*   ei  = (const int*)d_in[1];
    const float* Wmu = (const float*)d_in[2];
    const float* bmu = (const float*)d_in[3];
    const float* Wls = (const float*)d_in[4];
    const float* bls = (const float*)d_in[5];
    float* out = (float*)d_out;

    const int* row = ei;            // edge_index[0] (sources)
    const int* col = ei + N_EDGES;  // edge_index[1] (targets)

    // ws layout:
    //   bptr   int[NBUCK]       @ 0        (3.1 KB)
    //   dinv   f32[100096]      @ 8 KB     (400 KB, middle path only)
    //   hbf    u32[100000*10]   @ 512 KB   (4 MB, AoS bf16 prescaled h)
    //   bpairs int[NBUCK*CAP]   @ 4.5 MB   (15.2 MB)
    //   h32    f32[100000*20]   @ 20 MB    (8 MB, fast path only)
    const size_t BPAIRS_OFF = (size_t)(9 << 19);   // 4.5 MiB
    const size_t REQ  = BPAIRS_OFF + (size_t)NBUCK * CAP * 4;      // ~19.0 MiB
    const size_t H32_OFF = (size_t)20 << 20;                       // 20 MiB
    const size_t REQ2 = H32_OFF + (size_t)N_NODES * NC * 4;        // ~27.6 MiB (R10-proven available)

    if (ws_size >= REQ2) {
        char* w = (char*)d_ws;
        int*      bptr   = (int*)(w);
        unsigned* hbf    = (unsigned*)(w + (512 << 10));
        int*      bpairs = (int*)(w + BPAIRS_OFF);
        float*    h32    = (float*)(w + H32_OFF);

        k_initptr<<<(NBUCK + 255) / 256, 256, 0, stream>>>(bptr);
        k_mega32<<<NMEGA, 1024, 0, stream>>>(row, col, bptr, bpairs, x, Wmu, Wls, h32);
        k_degs_aos<<<NBUCK, 256, 0, stream>>>(bptr, bpairs, h32, hbf);
        k_agg4<<<NBUCK, 256, 0, stream>>>(bptr, bpairs, hbf, bmu, bls, out);
    } else if (ws_size >= REQ) {
        char* w = (char*)d_ws;
        int*      bptr   = (int*)(w);
        float*    dinv   = (float*)(w + 8192);
        unsigned* hbf    = (unsigned*)(w + (512 << 10));
        int*      bpairs = (int*)(w + BPAIRS_OFF);

        k_initptr<<<(NBUCK + 255) / 256, 256, 0, stream>>>(bptr);
        k_bin3<<<NCHUNK3, 1024, 0, stream>>>(row, col, bptr, bpairs);
        k_deg<<<NBUCK, 256, 0, stream>>>(bptr, bpairs, dinv);
        k_gemm6<<<(N_NODES + 127) / 128, 256, 0, stream>>>(x, Wmu, Wls, dinv, hbf);
        k_agg4<<<NBUCK, 256, 0, stream>>>(bptr, bpairs, hbf, bmu, bls, out);
    } else {
        float* deg = (float*)d_ws;
        float* h   = (float*)((char*)d_ws + (1 << 20));
        hipMemsetAsync(d_out, 0, (size_t)out_size * sizeof(float), stream);
        k_init_deg<<<(N_NODES + 255) / 256, 256, 0, stream>>>(deg);
        k_count<<<(N_EDGES + 255) / 256, 256, 0, stream>>>(col, deg);
        k_dinvk<<<(N_NODES + 255) / 256, 256, 0, stream>>>(deg);
        k_gemm_f32<<<(N_NODES + 255) / 256, 256, 0, stream>>>(x, Wmu, Wls, h);
        k_scatter<<<(N_EDGES + 255) / 256, 256, 0, stream>>>(row, col, deg, h, out);
        k_final<<<(N_NODES * OC + 255) / 256, 256, 0, stream>>>(h, deg, bmu, bls, out);
    }
}

// Round 12
// 263.287 us; speedup vs baseline: 1.1769x; 1.0437x over previous
//
#include <hip/hip_runtime.h>
#include <math.h>

#define N_NODES 100000
#define N_EDGES 3200000
#define IN_CH 256
#define NC 20        // combined output channels (10 mu + 10 logstd)
#define OC 10
#define NPB 128      // nodes per bucket (col >> 7)
#define NBUCK 782    // ceil(100000/128)
#define CAP 4864     // per-bucket capacity: mean 4096, sigma ~64 -> +12 sigma

// binning geometry: LDS counting sort, coalesced flush
#define CHUNK3 8192          // edges per block
#define NCHUNK3 391          // ceil(3.2M/8192)

// ---------- bf16 pack helpers (RNE) ----------
__device__ __forceinline__ unsigned bfpack(float a, float b) {
    unsigned ua = __float_as_uint(a), ub = __float_as_uint(b);
    ua = (ua + 0x7FFFu + ((ua >> 16) & 1u)) >> 16;
    ub = (ub + 0x7FFFu + ((ub >> 16) & 1u)) >> 16;
    return ua | (ub << 16);
}
__device__ __forceinline__ float bflo(unsigned p) { return __uint_as_float(p << 16); }
__device__ __forceinline__ float bfhi(unsigned p) { return __uint_as_float(p & 0xFFFF0000u); }

// ---------- LDS counting-sort binning (R1-proven); cursors are COUNTS (memset-init) ----------
// R6 lesson: NO global scatter-atomics to small arrays (cross-XCD ping-pong).
__global__ __launch_bounds__(1024) void k_bin3c(const int* __restrict__ row,
                                                const int* __restrict__ col,
                                                int* __restrict__ bcnt,
                                                int* __restrict__ bpairs) {
    __shared__ int   lh[NBUCK];      // counts -> scatter cursor
    __shared__ int   lscan[NBUCK];   // inclusive scan
    __shared__ int   gmino[NBUCK];   // gbase - lofs  (flush: dst = gmino[b] + j)
    __shared__ int   stage[CHUNK3];  // bucket-sorted packed pairs
    __shared__ unsigned short sbkt[CHUNK3];  // bucket id per staged slot

    int t = threadIdx.x;
    int e0 = blockIdx.x * CHUNK3;
    int nE = N_EDGES - e0; if (nE > CHUNK3) nE = CHUNK3;
    int n4 = nE >> 2;                 // chunk sizes divisible by 4
    const int4* c4 = (const int4*)(col + e0);
    const int4* r4 = (const int4*)(row + e0);

    for (int i = t; i < NBUCK; i += 1024) lh[i] = 0;
    __syncthreads();

    // phase 1: chunk histogram
    for (int j = t; j < n4; j += 1024) {
        int4 c = c4[j];
        atomicAdd(&lh[c.x >> 7], 1); atomicAdd(&lh[c.y >> 7], 1);
        atomicAdd(&lh[c.z >> 7], 1); atomicAdd(&lh[c.w >> 7], 1);
    }
    __syncthreads();

    // phase 2: inclusive scan over NBUCK
    int cnt = 0;
    if (t < NBUCK) { cnt = lh[t]; lscan[t] = cnt; }
    __syncthreads();
    for (int o = 1; o < NBUCK; o <<= 1) {
        int add = 0;
        if (t < NBUCK && t >= o) add = lscan[t - o];
        __syncthreads();
        if (t < NBUCK) lscan[t] += add;
        __syncthreads();
    }
    // phase 3: reserve global space per bucket (count-based cursors, start at 0)
    if (t < NBUCK) {
        int lofs = lscan[t] - cnt;
        int old = cnt ? atomicAdd(&bcnt[t], cnt) : 0;
        gmino[t] = (t * CAP + old) - lofs;
        lh[t] = lofs;                 // scatter cursor starts at local offset
    }
    __syncthreads();

    // phase 4: scatter into LDS, bucket-sorted
    for (int j = t; j < n4; j += 1024) {
        int4 c = c4[j];
        int4 r = r4[j];
        int b0 = c.x >> 7, b1 = c.y >> 7, b2 = c.z >> 7, b3 = c.w >> 7;
        int s0 = atomicAdd(&lh[b0], 1);
        int s1 = atomicAdd(&lh[b1], 1);
        int s2 = atomicAdd(&lh[b2], 1);
        int s3 = atomicAdd(&lh[b3], 1);
        stage[s0] = (r.x << 7) | (c.x & 127); sbkt[s0] = (unsigned short)b0;
        stage[s1] = (r.y << 7) | (c.y & 127); sbkt[s1] = (unsigned short)b1;
        stage[s2] = (r.z << 7) | (c.z & 127); sbkt[s2] = (unsigned short)b2;
        stage[s3] = (r.w << 7) | (c.w & 127); sbkt[s3] = (unsigned short)b3;
    }
    __syncthreads();

    // phase 5: coalesced flush — consecutive lanes hit consecutive dst inside runs
    for (int j = t; j < nE; j += 1024) {
        int b = sbkt[j];
        int dst = gmino[b] + j;
        if (dst < (b + 1) * CAP) bpairs[dst] = stage[j];
    }
}

// ---------- degree + per-node scan meta (deletes agg's duplicate hist+scan) ----------
// dinv[node] = rsqrt(deg+1); smeta[node] = (exclusive_base << 13) | cnt  (both < 8192)
__global__ __launch_bounds__(256) void k_deg3(const int* __restrict__ bcnt,
                                              const int* __restrict__ bpairs,
                                              float* __restrict__ dinv,
                                              int* __restrict__ smeta) {
    __shared__ int lc[NPB];
    __shared__ int lsc[NPB];
    int b = blockIdx.x, t = threadIdx.x;
    if (t < NPB) lc[t] = 0;
    __syncthreads();
    int n = bcnt[b]; if (n > CAP) n = CAP;
    int start = b * CAP;
    for (int p = t; p < n; p += 256)
        atomicAdd(&lc[bpairs[start + p] & 127], 1);
    __syncthreads();
    int cnt = 0;
    if (t < NPB) { cnt = lc[t]; lsc[t] = cnt; }
    __syncthreads();
    for (int o = 1; o < NPB; o <<= 1) {
        int add = 0;
        if (t < NPB && t >= o) add = lsc[t - o];
        __syncthreads();
        if (t < NPB) lsc[t] += add;
        __syncthreads();
    }
    int node = b * NPB + t;
    if (t < NPB && node < N_NODES) {
        dinv[node]  = rsqrtf((float)(cnt + 1));      // +1 self loop
        smeta[node] = ((lsc[t] - cnt) << 13) | cnt;  // excl base | count
    }
}

// ---------- skinny GEMM (R4-proven gemm6, verbatim; AoS prescaled bf16 out) ----------
// unroll-4 keeps the 4 loads of each 64B x-line consecutive (R5 lesson: breaking
// this costs 3.5x FETCH). G=2 nodes/thread, 782 blocks.
__global__ __launch_bounds__(256) void k_gemm6(const float* __restrict__ x,
                                               const float* __restrict__ Wmu,
                                               const float* __restrict__ Wls,
                                               const float* __restrict__ dinv,
                                               unsigned* __restrict__ hbf) {
    __shared__ float sW[NC * 272];
    int t = threadIdx.x;
    for (int idx = t; idx < IN_CH * OC; idx += 256) {
        int k = idx / OC, c = idx - (idx / OC) * OC;
        int kk = k >> 6, j = k & 63;
        sW[c * 272 + kk * 68 + j]          = Wmu[idx];
        sW[(c + OC) * 272 + kk * 68 + j]   = Wls[idx];
    }
    __syncthreads();

    int kk = t & 3;
    int slot = t >> 2;                       // 0..63
    int n0 = blockIdx.x * 128 + slot;        // thread's nodes: n0, n0+64

    int nd[2];
#pragma unroll
    for (int u = 0; u < 2; u++) {
        int n = n0 + u * 64;
        nd[u] = (n < N_NODES) ? n : (N_NODES - 1);   // clamp for safe loads
    }

    float acc[2][NC];
#pragma unroll
    for (int u = 0; u < 2; u++)
#pragma unroll
        for (int c = 0; c < NC; c++) acc[u][c] = 0.0f;

    const float4* x4 = (const float4*)x;

#pragma unroll 4
    for (int j4 = 0; j4 < 16; j4++) {
        float4 xv0 = x4[(size_t)nd[0] * 64 + kk * 16 + j4];
        float4 xv1 = x4[(size_t)nd[1] * 64 + kk * 16 + j4];
#pragma unroll
        for (int c = 0; c < NC; c++) {
            float4 w = *(const float4*)&sW[c * 272 + kk * 68 + j4 * 4];
            acc[0][c] += xv0.x * w.x + xv0.y * w.y + xv0.z * w.z + xv0.w * w.w;
            acc[1][c] += xv1.x * w.x + xv1.y * w.y + xv1.z * w.z + xv1.w * w.w;
        }
    }

    // quad reduction (lanes node*4+kk, quads lane-aligned)
#pragma unroll
    for (int u = 0; u < 2; u++)
#pragma unroll
        for (int c = 0; c < NC; c++) {
            acc[u][c] += __shfl_xor(acc[u][c], 2);
            acc[u][c] += __shfl_xor(acc[u][c], 1);
        }

    if (kk == 0) {
#pragma unroll
        for (int u = 0; u < 2; u++) {
            int n = n0 + u * 64;
            if (n >= N_NODES) continue;
            float d = dinv[n];
            unsigned* hp = hbf + (size_t)n * 10;
            *(uint2*)(hp + 0) = make_uint2(bfpack(acc[u][0] * d,  acc[u][1] * d),
                                           bfpack(acc[u][2] * d,  acc[u][3] * d));
            *(uint2*)(hp + 2) = make_uint2(bfpack(acc[u][4] * d,  acc[u][5] * d),
                                           bfpack(acc[u][6] * d,  acc[u][7] * d));
            *(uint2*)(hp + 4) = make_uint2(bfpack(acc[u][8] * d,  acc[u][9] * d),
                                           bfpack(acc[u][10] * d, acc[u][11] * d));
            *(uint2*)(hp + 6) = make_uint2(bfpack(acc[u][12] * d, acc[u][13] * d),
                                           bfpack(acc[u][14] * d, acc[u][15] * d));
            *(uint2*)(hp + 8) = make_uint2(bfpack(acc[u][16] * d, acc[u][17] * d),
                                           bfpack(acc[u][18] * d, acc[u][19] * d));
        }
    }
}

// ---------- sort+reduce, LITE: hist+scan deleted (smeta from k_deg3) ----------
__global__ __launch_bounds__(256) void k_agg4L(const int* __restrict__ bcnt,
                                               const int* __restrict__ bpairs,
                                               const unsigned* __restrict__ hbf,
                                               const int* __restrict__ smeta,
                                               const float* __restrict__ bmu,
                                               const float* __restrict__ bls,
                                               float* __restrict__ out) {
    __shared__ int lcnt[NPB];    // scatter cursor (starts at excl base)
    __shared__ int sBase[NPB];   // per-node exclusive base
    __shared__ int sCnt[NPB];    // per-node count
    __shared__ int ssrc[CAP];    // node-sorted src ids
    int b = blockIdx.x, t = threadIdx.x;
    int start = b * CAP;
    int n = bcnt[b]; if (n > CAP) n = CAP;

    if (t < NPB) {
        int node = b * NPB + t;
        int m = (node < N_NODES) ? smeta[node] : 0;
        int base = m >> 13, cnt = m & 8191;
        sBase[t] = base; sCnt[t] = cnt; lcnt[t] = base;
    }
    __syncthreads();

    // single bpairs pass: scatter into node-sorted LDS
    for (int p = t; p < n; p += 256) {
        int pk = bpairs[start + p];
        int q = atomicAdd(&lcnt[pk & 127], 1);
        ssrc[q] = ((unsigned)pk) >> 7;
    }
    __syncthreads();

    // reduce: 2 threads per node, edge-split halves, shuffle combine
    int nl = t >> 1, half = t & 1;
    int node = b * NPB + nl;
    int ccnt = sCnt[nl];
    int base = sBase[nl];
    int mid = ccnt >> 1;
    int j0 = half ? mid : 0;
    int j1 = half ? ccnt : mid;

    float a[NC];
#pragma unroll
    for (int c = 0; c < NC; c++) a[c] = 0.0f;

#define ADDROW(R)                                                        \
    {                                                                    \
        const unsigned* hp_ = hbf + (size_t)(R) * 10;                    \
        uint2 q0 = *(const uint2*)(hp_ + 0);                             \
        uint2 q1 = *(const uint2*)(hp_ + 2);                             \
        uint2 q2 = *(const uint2*)(hp_ + 4);                             \
        uint2 q3 = *(const uint2*)(hp_ + 6);                             \
        uint2 q4 = *(const uint2*)(hp_ + 8);                             \
        a[0]  += bflo(q0.x); a[1]  += bfhi(q0.x);                        \
        a[2]  += bflo(q0.y); a[3]  += bfhi(q0.y);                        \
        a[4]  += bflo(q1.x); a[5]  += bfhi(q1.x);                        \
        a[6]  += bflo(q1.y); a[7]  += bfhi(q1.y);                        \
        a[8]  += bflo(q2.x); a[9]  += bfhi(q2.x);                        \
        a[10] += bflo(q2.y); a[11] += bfhi(q2.y);                        \
        a[12] += bflo(q3.x); a[13] += bfhi(q3.x);                        \
        a[14] += bflo(q3.y); a[15] += bfhi(q3.y);                        \
        a[16] += bflo(q4.x); a[17] += bfhi(q4.x);                        \
        a[18] += bflo(q4.y); a[19] += bfhi(q4.y);                        \
    }

    int j = j0;
    for (; j + 1 < j1; j += 2) {
        int r0 = ssrc[base + j];
        int r1 = ssrc[base + j + 1];
        ADDROW(r0);
        ADDROW(r1);
    }
    if (j < j1) {
        int r0 = ssrc[base + j];
        ADDROW(r0);
    }
    // self loop (h' already carries dinv[node]) on the even-half thread
    if (half == 0 && node < N_NODES) ADDROW(node);
#undef ADDROW

#pragma unroll
    for (int c = 0; c < NC; c++) a[c] += __shfl_xor(a[c], 1);

    if (half == 0 && node < N_NODES) {
        float dn = rsqrtf((float)(ccnt + 1));
        float* om = out + (size_t)node * OC;
        float* ol = out + (size_t)N_NODES * OC + (size_t)node * OC;
#pragma unroll
        for (int c = 0; c < OC; c++) {
            om[c] = dn * a[c]      + bmu[c];
            ol[c] = dn * a[c + OC] + bls[c];
        }
    }
}

// ======================= fallback (atomic scatter path, tiny ws) =======================
__global__ __launch_bounds__(256) void k_init_deg(float* __restrict__ deg) {
    int i = blockIdx.x * 256 + threadIdx.x;
    if (i < N_NODES) deg[i] = 1.0f;
}
__global__ __launch_bounds__(256) void k_count(const int* __restrict__ col, float* __restrict__ deg) {
    int e = blockIdx.x * 256 + threadIdx.x;
    if (e < N_EDGES) atomicAdd(&deg[col[e]], 1.0f);
}
__global__ __launch_bounds__(256) void k_dinvk(float* __restrict__ deg) {
    int i = blockIdx.x * 256 + threadIdx.x;
    if (i < N_NODES) deg[i] = rsqrtf(deg[i]);
}
__global__ __launch_bounds__(256) void k_gemm_f32(const float* __restrict__ x,
                                                  const float* __restrict__ Wmu,
                                                  const float* __restrict__ Wls,
                                                  float* __restrict__ h) {
    int node = blockIdx.x * 256 + threadIdx.x;
    if (node >= N_NODES) return;
    const float4* x4 = (const float4*)(x + (size_t)node * IN_CH);
    float acc[NC];
#pragma unroll
    for (int c = 0; c < NC; c++) acc[c] = 0.0f;
    for (int k4 = 0; k4 < IN_CH / 4; k4++) {
        float4 xv = x4[k4];
        float xk[4] = {xv.x, xv.y, xv.z, xv.w};
#pragma unroll
        for (int kk = 0; kk < 4; kk++) {
            const float* wm = Wmu + (k4 * 4 + kk) * OC;
            const float* wl = Wls + (k4 * 4 + kk) * OC;
#pragma unroll
            for (int c = 0; c < OC; c++) {
                acc[c]      += xk[kk] * wm[c];
                acc[c + OC] += xk[kk] * wl[c];
            }
        }
    }
    float* hp = h + (size_t)node * NC;
#pragma unroll
    for (int c = 0; c < NC; c++) hp[c] = acc[c];
}
__global__ __launch_bounds__(256) void k_scatter(const int* __restrict__ row, const int* __restrict__ col,
                                                 const float* __restrict__ dinv, const float* __restrict__ h,
                                                 float* __restrict__ out) {
    int e = blockIdx.x * 256 + threadIdx.x;
    if (e >= N_EDGES) return;
    int r = row[e], c = col[e];
    float s = dinv[r] * dinv[c];
    const float* hp = h + (size_t)r * NC;
    float* om = out + (size_t)c * OC;
    float* ol = om + (size_t)N_NODES * OC;
#pragma unroll
    for (int k = 0; k < OC; k++) atomicAdd(om + k, hp[k] * s);
#pragma unroll
    for (int k = 0; k < OC; k++) atomicAdd(ol + k, hp[OC + k] * s);
}
__global__ __launch_bounds__(256) void k_final(const float* __restrict__ h, const float* __restrict__ dinv,
                                               const float* __restrict__ bmu, const float* __restrict__ bls,
                                               float* __restrict__ out) {
    int i = blockIdx.x * 256 + threadIdx.x;
    if (i >= N_NODES * OC) return;
    int node = i / OC, c = i - node * OC;
    float d = dinv[node];
    float d2 = d * d;
    out[i]                += h[node * NC + c]      * d2 + bmu[c];
    out[N_NODES * OC + i] += h[node * NC + OC + c] * d2 + bls[c];
}

extern "C" void kernel_launch(void* const* d_in, const int* in_sizes, int n_in,
                              void* d_out, int out_size, void* d_ws, size_t ws_size,
                              hipStream_t stream) {
    const float* x   = (const float*)d_in[0];
    const int*   ei  = (const int*)d_in[1];
    const float* Wmu = (const float*)d_in[2];
    const float* bmu = (const float*)d_in[3];
    const float* Wls = (const float*)d_in[4];
    const float* bls = (const float*)d_in[5];
    float* out = (float*)d_out;

    const int* row = ei;            // edge_index[0] (sources)
    const int* col = ei + N_EDGES;  // edge_index[1] (targets)

    // ws layout:
    //   bcnt   int[NBUCK]       @ 0        (3.1 KB, memset to 0)
    //   dinv   f32[100096]      @ 8 KB     (400 KB)
    //   smeta  int[100096]      @ 416 KB   (400 KB; (base<<13)|cnt per node)
    //   hbf    u32[100000*10]   @ 1 MB     (4 MB, AoS bf16 prescaled h)
    //   bpairs int[NBUCK*CAP]   @ 5 MB     (14.5 MiB; packed (row<<7)|(col&127))
    const size_t HBF_OFF    = (size_t)1 << 20;
    const size_t BPAIRS_OFF = (size_t)5 << 20;
    const size_t REQ = BPAIRS_OFF + (size_t)NBUCK * CAP * 4;   // ~19.5 MiB (< 27.6 proven)

    if (ws_size >= REQ) {
        char* w = (char*)d_ws;
        int*      bcnt   = (int*)(w);
        float*    dinv   = (float*)(w + 8192);
        int*      smeta  = (int*)(w + (416 << 10));
        unsigned* hbf    = (unsigned*)(w + HBF_OFF);
        int*      bpairs = (int*)(w + BPAIRS_OFF);

        hipMemsetAsync(bcnt, 0, NBUCK * sizeof(int), stream);
        k_bin3c<<<NCHUNK3, 1024, 0, stream>>>(row, col, bcnt, bpairs);
        k_deg3<<<NBUCK, 256, 0, stream>>>(bcnt, bpairs, dinv, smeta);
        k_gemm6<<<(N_NODES + 127) / 128, 256, 0, stream>>>(x, Wmu, Wls, dinv, hbf);
        k_agg4L<<<NBUCK, 256, 0, stream>>>(bcnt, bpairs, hbf, smeta, bmu, bls, out);
    } else {
        float* deg = (float*)d_ws;
        float* h   = (float*)((char*)d_ws + (1 << 20));
        hipMemsetAsync(d_out, 0, (size_t)out_size * sizeof(float), stream);
        k_init_deg<<<(N_NODES + 255) / 256, 256, 0, stream>>>(deg);
        k_count<<<(N_EDGES + 255) / 256, 256, 0, stream>>>(col, deg);
        k_dinvk<<<(N_NODES + 255) / 256, 256, 0, stream>>>(deg);
        k_gemm_f32<<<(N_NODES + 255) / 256, 256, 0, stream>>>(x, Wmu, Wls, h);
        k_scatter<<<(N_EDGES + 255) / 256, 256, 0, stream>>>(row, col, deg, h, out);
        k_final<<<(N_NODES * OC + 255) / 256, 256, 0, stream>>>(h, deg, bmu, bls, out);
    }
}